// Round 10
// baseline (573.776 us; speedup 1.0000x reference)
//
#include <hip/hip_runtime.h>
#include <math.h>
#include <stdint.h>

#define N_NODES 100000
#define NBK 512         // mega-kernel grid blocks
#define TPB 512         // threads per block (8 waves)
#define NP 256          // buckets (dst >> 9), 512 nodes per bucket
#define BSH 9
#define BMASK 511u
#define G 8             // lanes per node in conv gathers

// ---------------- device-scope grid barrier (persistent kernel) ----------------
// Correctness: __syncthreads makes block-local writes block-visible; thread0's
// __threadfence (agent scope on gfx950 = cache-wide L2 wb) releases them
// device-wide before the atomic arrive; after the spin, the second fence
// (cache-wide inv) acquires remote writes; __syncthreads publishes to the block.
__device__ __forceinline__ void grid_sync(int* bar, int& gen) {
    __syncthreads();
    gen += NBK;
    if (threadIdx.x == 0) {
        __threadfence();
        atomicAdd(bar, 1);
        while (atomicAdd(bar, 0) < gen) __builtin_amdgcn_s_sleep(8);
        __threadfence();
    }
    __syncthreads();
}

__device__ __forceinline__ void gather_sum(const int* __restrict__ col,
                                           const float4* __restrict__ tab,
                                           int beg, int end, int g,
                                           float& s0, float& s1, float& s2) {
    int k = beg + g;
    for (; k + 3*G < end; k += 4*G) {
        int c0 = col[k], c1 = col[k+G], c2 = col[k+2*G], c3 = col[k+3*G];
        float4 v0 = tab[c0], v1 = tab[c1], v2 = tab[c2], v3 = tab[c3];
        s0 += v0.x; s1 += v0.y; s2 += v0.z;
        s0 += v1.x; s1 += v1.y; s2 += v1.z;
        s0 += v2.x; s1 += v2.y; s2 += v2.z;
        s0 += v3.x; s1 += v3.y; s2 += v3.z;
    }
    for (; k < end; k += G) {
        float4 v = tab[col[k]];
        s0 += v.x; s1 += v.y; s2 += v.z;
    }
}

// =========================== the mega kernel ===========================
__global__ __launch_bounds__(TPB, 4) void k_mega(
    const int* __restrict__ src, const int* __restrict__ dst, int E, int vec_ok,
    const float* __restrict__ x,
    const float* __restrict__ W1, const float* __restrict__ b1,
    const float* __restrict__ W2, const float* __restrict__ b2,
    const float* __restrict__ W3, const float* __restrict__ b3,
    const float* __restrict__ Wp, const float* __restrict__ bp,
    const float* __restrict__ Wl, const float* __restrict__ bl,
    int* __restrict__ hist, int* __restrict__ totals, int* __restrict__ base,
    int* __restrict__ offs, unsigned int* __restrict__ part,
    float4* __restrict__ bufA, float4* __restrict__ bufB,
    int* __restrict__ col, float* __restrict__ pool, int* __restrict__ bar,
    float* __restrict__ hout, float* __restrict__ emb, float* __restrict__ out10,
    int N)
{
    __shared__ int bin[NP];
    __shared__ int colcache[NBK];
    __shared__ int scanbuf[NBK];
    __shared__ int cnt[512];
    __shared__ int scn[512];
    __shared__ int curs[512];
    __shared__ float wsum[TPB/64][3];

    const int t = threadIdx.x;
    const int b = blockIdx.x;
    int gen = 0;

    // ---------------- P0: per-block bucket histogram ----------------
    if (t < NP) bin[t] = 0;
    __syncthreads();
    if (vec_ok) {
        int ngroups = E >> 2;
        int gchunk = (ngroups + NBK - 1) / NBK;
        int gbeg = b * gchunk;
        int gend = gbeg + gchunk; if (gend > ngroups) gend = ngroups;
        const int4* d4 = (const int4*)dst;
        for (int g = gbeg + t; g < gend; g += TPB) {
            int4 d = d4[g];
            atomicAdd(&bin[d.x >> BSH], 1);
            atomicAdd(&bin[d.y >> BSH], 1);
            atomicAdd(&bin[d.z >> BSH], 1);
            atomicAdd(&bin[d.w >> BSH], 1);
        }
        if (b == 0) {
            for (int e = (ngroups << 2) + t; e < E; e += TPB)
                atomicAdd(&bin[dst[e] >> BSH], 1);
        }
    } else {
        int echunk = (E + NBK - 1) / NBK;
        int ebeg = b * echunk;
        int eend = ebeg + echunk; if (eend > E) eend = E;
        for (int e = ebeg + t; e < eend; e += TPB)
            atomicAdd(&bin[dst[e] >> BSH], 1);
    }
    __syncthreads();
    if (t < NP) hist[b * NP + t] = bin[t];
    grid_sync(bar, gen);

    // ---------------- P1: bucket column totals (block b owns bucket b) -------
    if (b < NP) {
        colcache[t] = hist[t * NP + b];     // column b, cached in LDS
        scanbuf[t] = colcache[t];
        __syncthreads();
        #pragma unroll
        for (int s = TPB/2; s > 0; s >>= 1) {
            if (t < s) scanbuf[t] += scanbuf[t + s];
            __syncthreads();
        }
        if (t == 0) totals[b] = scanbuf[0];
    }
    grid_sync(bar, gen);

    // ---------------- P2: bucket base scan + rewrite hist with bases ----------
    if (b < NP) {
        int tot = (t < NP) ? totals[t] : 0;
        scanbuf[t] = tot;
        __syncthreads();
        for (int off = 1; off < TPB; off <<= 1) {
            int u = (t >= off) ? scanbuf[t - off] : 0;
            __syncthreads();
            scanbuf[t] += u;
            __syncthreads();
        }
        int base_b = scanbuf[b] - totals[b];        // exclusive prefix at b
        if (b == 0) {
            if (t < NP) base[t] = scanbuf[t] - totals[t];
            if (t == 0) base[NP] = scanbuf[NP - 1]; // = E
        }
        // exclusive scan of the cached column over k
        int v = colcache[t];
        scanbuf[t] = v;
        __syncthreads();
        for (int off = 1; off < TPB; off <<= 1) {
            int u = (t >= off) ? scanbuf[t - off] : 0;
            __syncthreads();
            scanbuf[t] += u;
            __syncthreads();
        }
        hist[t * NP + b] = base_b + scanbuf[t] - v;
    }
    grid_sync(bar, gen);

    // ---------------- P3: partition edges -> part[] ----------------
    if (t < NP) curs[t] = hist[b * NP + t];
    __syncthreads();
    if (vec_ok) {
        int ngroups = E >> 2;
        int gchunk = (ngroups + NBK - 1) / NBK;
        int gbeg = b * gchunk;
        int gend = gbeg + gchunk; if (gend > ngroups) gend = ngroups;
        const int4* d4 = (const int4*)dst;
        const int4* s4 = (const int4*)src;
        for (int g = gbeg + t; g < gend; g += TPB) {
            int4 d = d4[g];
            int4 s = s4[g];
            int p;
            p = atomicAdd(&curs[d.x >> BSH], 1);
            part[p] = ((unsigned)s.x << BSH) | ((unsigned)d.x & BMASK);
            p = atomicAdd(&curs[d.y >> BSH], 1);
            part[p] = ((unsigned)s.y << BSH) | ((unsigned)d.y & BMASK);
            p = atomicAdd(&curs[d.z >> BSH], 1);
            part[p] = ((unsigned)s.z << BSH) | ((unsigned)d.z & BMASK);
            p = atomicAdd(&curs[d.w >> BSH], 1);
            part[p] = ((unsigned)s.w << BSH) | ((unsigned)d.w & BMASK);
        }
        if (b == 0) {
            for (int e = (ngroups << 2) + t; e < E; e += TPB) {
                int d = dst[e];
                int p = atomicAdd(&curs[d >> BSH], 1);
                part[p] = ((unsigned)src[e] << BSH) | ((unsigned)d & BMASK);
            }
        }
    } else {
        int echunk = (E + NBK - 1) / NBK;
        int ebeg = b * echunk;
        int eend = ebeg + echunk; if (eend > E) eend = E;
        for (int e = ebeg + t; e < eend; e += TPB) {
            int d = dst[e];
            int p = atomicAdd(&curs[d >> BSH], 1);
            part[p] = ((unsigned)src[e] << BSH) | ((unsigned)d & BMASK);
        }
    }
    grid_sync(bar, gen);

    // ---------------- P4: per-bucket CSR + prescale xp4 ----------------
    if (b < NP) {
        int lo = base[b], hi = base[b + 1];
        cnt[t] = 0;
        __syncthreads();
        for (int e = lo + t; e < hi; e += TPB)
            atomicAdd(&cnt[part[e] & BMASK], 1);
        __syncthreads();
        int v = cnt[t];
        scn[t] = v;
        __syncthreads();
        for (int off = 1; off < 512; off <<= 1) {
            int u = (t >= off) ? scn[t - off] : 0;
            __syncthreads();
            scn[t] += u;
            __syncthreads();
        }
        {
            int pos = lo + scn[t] - v;        // exclusive
            curs[t] = pos;
            int gnode = (b << BSH) + t;
            if (gnode < N) {
                offs[gnode] = pos;
                float di = rsqrtf((float)(v + 1));   // +1 self-loop
                bufA[gnode] = make_float4(x[3*gnode] * di, x[3*gnode+1] * di,
                                          x[3*gnode+2] * di, di);
            }
        }
        if (b == 0 && t == 0) offs[N] = E;
        __syncthreads();
        for (int e = lo + t; e < hi; e += TPB) {
            unsigned int w = part[e];
            int p = atomicAdd(&curs[w & BMASK], 1);
            col[p] = (int)(w >> BSH);
        }
    }
    grid_sync(bar, gen);

    // ---------------- P5: conv1 (bufA -> bufB) ----------------
    const int ntask = N * G;
    const int stride = NBK * TPB;
    for (int nt = b * TPB + t; nt < ntask; nt += stride) {
        int i = nt >> 3, g = nt & (G - 1);
        float s0 = 0.f, s1 = 0.f, s2 = 0.f, di = 0.f;
        if (g == 0) {
            float4 self = bufA[i];
            s0 = self.x; s1 = self.y; s2 = self.z; di = self.w;
        }
        gather_sum(col, bufA, offs[i], offs[i+1], g, s0, s1, s2);
        #pragma unroll
        for (int off = G/2; off > 0; off >>= 1) {
            s0 += __shfl_down(s0, off, G);
            s1 += __shfl_down(s1, off, G);
            s2 += __shfl_down(s2, off, G);
        }
        if (g == 0) {
            float g0 = s0 * di, g1 = s1 * di, g2 = s2 * di;
            float o0 = 0.f, o1 = 0.f, o2 = 0.f;
            #pragma unroll
            for (int j = 0; j < 16; ++j) {
                float tv = fmaxf(g0 * W1[j] + g1 * W1[16 + j] + g2 * W1[32 + j] + b1[j], 0.f);
                o0 += tv * W2[3*j + 0];
                o1 += tv * W2[3*j + 1];
                o2 += tv * W2[3*j + 2];
            }
            bufB[i] = make_float4(o0 * di, o1 * di, o2 * di, di);
        }
    }
    grid_sync(bar, gen);

    // ---------------- P6: conv2 (bufB -> bufA, emb out) ----------------
    for (int nt = b * TPB + t; nt < ntask; nt += stride) {
        int i = nt >> 3, g = nt & (G - 1);
        float s0 = 0.f, s1 = 0.f, s2 = 0.f, di = 0.f;
        if (g == 0) {
            float4 self = bufB[i];
            s0 = self.x; s1 = self.y; s2 = self.z; di = self.w;
        }
        gather_sum(col, bufB, offs[i], offs[i+1], g, s0, s1, s2);
        #pragma unroll
        for (int off = G/2; off > 0; off >>= 1) {
            s0 += __shfl_down(s0, off, G);
            s1 += __shfl_down(s1, off, G);
            s2 += __shfl_down(s2, off, G);
        }
        if (g == 0) {
            float t0 = s0 * di + b2[0];
            float t1 = s1 * di + b2[1];
            float t2 = s2 * di + b2[2];
            float inv = 1.0f / fmaxf(sqrtf(t0*t0 + t1*t1 + t2*t2), 1e-12f);
            float e0 = t0*inv, e1 = t1*inv, e2 = t2*inv;
            emb[3*i] = e0; emb[3*i+1] = e1; emb[3*i+2] = e2;
            bufA[i] = make_float4((e0*W3[0] + e1*W3[3] + e2*W3[6]) * di,
                                  (e0*W3[1] + e1*W3[4] + e2*W3[7]) * di,
                                  (e0*W3[2] + e1*W3[5] + e2*W3[8]) * di, di);
        }
    }
    grid_sync(bar, gen);

    // ---------------- P7: conv3 (bufA -> hout) + block pool partial ----------
    {
        float p0 = 0.f, p1 = 0.f, p2 = 0.f;
        for (int nt = b * TPB + t; nt < ntask; nt += stride) {
            int i = nt >> 3, g = nt & (G - 1);
            float s0 = 0.f, s1 = 0.f, s2 = 0.f, di = 0.f;
            if (g == 0) {
                float4 self = bufA[i];
                s0 = self.x; s1 = self.y; s2 = self.z; di = self.w;
            }
            gather_sum(col, bufA, offs[i], offs[i+1], g, s0, s1, s2);
            #pragma unroll
            for (int off = G/2; off > 0; off >>= 1) {
                s0 += __shfl_down(s0, off, G);
                s1 += __shfl_down(s1, off, G);
                s2 += __shfl_down(s2, off, G);
            }
            if (g == 0) {
                float t0 = s0 * di + b3[0];
                float t1 = s1 * di + b3[1];
                float t2 = s2 * di + b3[2];
                float q0 = t0*Wp[0] + t1*Wp[3] + t2*Wp[6] + bp[0];
                float q1 = t0*Wp[1] + t1*Wp[4] + t2*Wp[7] + bp[1];
                float q2 = t0*Wp[2] + t1*Wp[5] + t2*Wp[8] + bp[2];
                hout[3*i] = q0; hout[3*i+1] = q1; hout[3*i+2] = q2;
                p0 += q0; p1 += q1; p2 += q2;
            }
        }
        #pragma unroll
        for (int off = 32; off > 0; off >>= 1) {
            p0 += __shfl_down(p0, off);
            p1 += __shfl_down(p1, off);
            p2 += __shfl_down(p2, off);
        }
        if ((t & 63) == 0) {
            int w = t >> 6;
            wsum[w][0] = p0; wsum[w][1] = p1; wsum[w][2] = p2;
        }
        __syncthreads();
        if (t == 0) {
            float a0 = 0.f, a1 = 0.f, a2 = 0.f;
            #pragma unroll
            for (int w = 0; w < TPB/64; ++w) {
                a0 += wsum[w][0]; a1 += wsum[w][1]; a2 += wsum[w][2];
            }
            pool[3*b] = a0; pool[3*b+1] = a1; pool[3*b+2] = a2;
        }
    }
    grid_sync(bar, gen);

    // ---------------- P8: head (block 0) ----------------
    if (b == 0) {
        float p0 = 0.f, p1 = 0.f, p2 = 0.f;
        for (int k = t; k < NBK; k += TPB) {
            p0 += pool[3*k]; p1 += pool[3*k+1]; p2 += pool[3*k+2];
        }
        #pragma unroll
        for (int off = 32; off > 0; off >>= 1) {
            p0 += __shfl_down(p0, off);
            p1 += __shfl_down(p1, off);
            p2 += __shfl_down(p2, off);
        }
        if ((t & 63) == 0) {
            int w = t >> 6;
            wsum[w][0] = p0; wsum[w][1] = p1; wsum[w][2] = p2;
        }
        __syncthreads();
        if (t == 0) {
            p0 = 0.f; p1 = 0.f; p2 = 0.f;
            #pragma unroll
            for (int w = 0; w < TPB/64; ++w) {
                p0 += wsum[w][0]; p1 += wsum[w][1]; p2 += wsum[w][2];
            }
            p0 /= (float)N; p1 /= (float)N; p2 /= (float)N;
            float l[10];
            float m = -1e30f;
            #pragma unroll
            for (int j = 0; j < 10; ++j) {
                l[j] = p0 * Wl[j] + p1 * Wl[10 + j] + p2 * Wl[20 + j] + bl[j];
                m = fmaxf(m, l[j]);
            }
            float s = 0.f;
            #pragma unroll
            for (int j = 0; j < 10; ++j) s += expf(l[j] - m);
            float lse = logf(s) + m;
            #pragma unroll
            for (int j = 0; j < 10; ++j) out10[j] = l[j] - lse;
        }
    }
}

// ================= fallback pipeline (global atomics, multi-kernel) ==========

__global__ void k_deg(const int* __restrict__ dst, int E, int* __restrict__ deg) {
    int e = blockIdx.x * blockDim.x + threadIdx.x;
    if (e < E) atomicAdd(&deg[dst[e]], 1);
}

__global__ void k_scan1(const int* __restrict__ deg, int* __restrict__ offs,
                        int* __restrict__ partl, int N) {
    __shared__ int sh[256];
    int i = blockIdx.x * 256 + threadIdx.x;
    int t = threadIdx.x;
    int v = (i < N) ? deg[i] : 0;
    sh[t] = v;
    __syncthreads();
    #pragma unroll
    for (int off = 1; off < 256; off <<= 1) {
        int u = (t >= off) ? sh[t - off] : 0;
        __syncthreads();
        sh[t] += u;
        __syncthreads();
    }
    if (i < N) offs[i] = sh[t] - v;
    if (t == 255) partl[blockIdx.x] = sh[255];
}

__global__ void k_scan2(int* __restrict__ partl, int* __restrict__ offs, int nb, int N) {
    __shared__ int sh[1024];
    int t = threadIdx.x;
    int v = (t < nb) ? partl[t] : 0;
    sh[t] = v;
    __syncthreads();
    #pragma unroll
    for (int off = 1; off < 1024; off <<= 1) {
        int u = (t >= off) ? sh[t - off] : 0;
        __syncthreads();
        sh[t] += u;
        __syncthreads();
    }
    if (t < nb) partl[t] = sh[t] - v;
    if (t == 1023) offs[N] = sh[1023];
}

__global__ void k_scan3(int* __restrict__ offs, const int* __restrict__ partl, int N) {
    int i = blockIdx.x * 256 + threadIdx.x;
    if (i < N) offs[i] += partl[blockIdx.x];
}

__global__ void k_fill_cur(const int* __restrict__ src, const int* __restrict__ dst,
                           const int* __restrict__ offs, int* __restrict__ cur,
                           int* __restrict__ col, int E) {
    int e = blockIdx.x * blockDim.x + threadIdx.x;
    if (e >= E) return;
    int d = dst[e];
    col[offs[d] + atomicAdd(&cur[d], 1)] = src[e];
}

__global__ void k_prescale(const float* __restrict__ x, const int* __restrict__ offs,
                           float4* __restrict__ xp4, int N) {
    int i = blockIdx.x * blockDim.x + threadIdx.x;
    if (i >= N) return;
    int d = offs[i+1] - offs[i];
    float di = rsqrtf((float)(d + 1));
    xp4[i] = make_float4(x[3*i] * di, x[3*i+1] * di, x[3*i+2] * di, di);
}

__global__ void k_conv1(const int* __restrict__ offs, const int* __restrict__ col,
                        const float4* __restrict__ xp4,
                        const float* __restrict__ W1, const float* __restrict__ b1,
                        const float* __restrict__ W2,
                        float4* __restrict__ h2p4, int N) {
    int tid = blockIdx.x * blockDim.x + threadIdx.x;
    int i = tid >> 3, g = tid & (G - 1);
    if (i >= N) return;
    float s0 = 0.f, s1 = 0.f, s2 = 0.f, di = 0.f;
    if (g == 0) {
        float4 self = xp4[i];
        s0 = self.x; s1 = self.y; s2 = self.z; di = self.w;
    }
    gather_sum(col, xp4, offs[i], offs[i+1], g, s0, s1, s2);
    #pragma unroll
    for (int off = G/2; off > 0; off >>= 1) {
        s0 += __shfl_down(s0, off, G);
        s1 += __shfl_down(s1, off, G);
        s2 += __shfl_down(s2, off, G);
    }
    if (g == 0) {
        float g0 = s0 * di, g1 = s1 * di, g2 = s2 * di;
        float o0 = 0.f, o1 = 0.f, o2 = 0.f;
        #pragma unroll
        for (int j = 0; j < 16; ++j) {
            float t = fmaxf(g0 * W1[j] + g1 * W1[16 + j] + g2 * W1[32 + j] + b1[j], 0.f);
            o0 += t * W2[3*j + 0];
            o1 += t * W2[3*j + 1];
            o2 += t * W2[3*j + 2];
        }
        h2p4[i] = make_float4(o0 * di, o1 * di, o2 * di, di);
    }
}

__global__ void k_conv2(const int* __restrict__ offs, const int* __restrict__ col,
                        const float4* __restrict__ h2p4,
                        const float* __restrict__ b2, const float* __restrict__ W3,
                        float* __restrict__ embed_out, float4* __restrict__ h3p4, int N) {
    int tid = blockIdx.x * blockDim.x + threadIdx.x;
    int i = tid >> 3, g = tid & (G - 1);
    if (i >= N) return;
    float s0 = 0.f, s1 = 0.f, s2 = 0.f, di = 0.f;
    if (g == 0) {
        float4 self = h2p4[i];
        s0 = self.x; s1 = self.y; s2 = self.z; di = self.w;
    }
    gather_sum(col, h2p4, offs[i], offs[i+1], g, s0, s1, s2);
    #pragma unroll
    for (int off = G/2; off > 0; off >>= 1) {
        s0 += __shfl_down(s0, off, G);
        s1 += __shfl_down(s1, off, G);
        s2 += __shfl_down(s2, off, G);
    }
    if (g == 0) {
        float t0 = s0 * di + b2[0];
        float t1 = s1 * di + b2[1];
        float t2 = s2 * di + b2[2];
        float inv = 1.0f / fmaxf(sqrtf(t0*t0 + t1*t1 + t2*t2), 1e-12f);
        float e0 = t0*inv, e1 = t1*inv, e2 = t2*inv;
        embed_out[3*i] = e0; embed_out[3*i+1] = e1; embed_out[3*i+2] = e2;
        h3p4[i] = make_float4((e0*W3[0] + e1*W3[3] + e2*W3[6]) * di,
                              (e0*W3[1] + e1*W3[4] + e2*W3[7]) * di,
                              (e0*W3[2] + e1*W3[5] + e2*W3[8]) * di, di);
    }
}

__global__ void k_conv3(const int* __restrict__ offs, const int* __restrict__ col,
                        const float4* __restrict__ h3p4,
                        const float* __restrict__ b3, const float* __restrict__ Wp,
                        const float* __restrict__ bp,
                        float* __restrict__ hout, float* __restrict__ pool, int N) {
    __shared__ float ws[4][3];
    int tid = blockIdx.x * blockDim.x + threadIdx.x;
    int i = tid >> 3, g = tid & (G - 1);
    float p0 = 0.f, p1 = 0.f, p2 = 0.f;
    if (i < N) {
        float s0 = 0.f, s1 = 0.f, s2 = 0.f, di = 0.f;
        if (g == 0) {
            float4 self = h3p4[i];
            s0 = self.x; s1 = self.y; s2 = self.z; di = self.w;
        }
        gather_sum(col, h3p4, offs[i], offs[i+1], g, s0, s1, s2);
        #pragma unroll
        for (int off = G/2; off > 0; off >>= 1) {
            s0 += __shfl_down(s0, off, G);
            s1 += __shfl_down(s1, off, G);
            s2 += __shfl_down(s2, off, G);
        }
        if (g == 0) {
            float t0 = s0 * di + b3[0];
            float t1 = s1 * di + b3[1];
            float t2 = s2 * di + b3[2];
            p0 = t0*Wp[0] + t1*Wp[3] + t2*Wp[6] + bp[0];
            p1 = t0*Wp[1] + t1*Wp[4] + t2*Wp[7] + bp[1];
            p2 = t0*Wp[2] + t1*Wp[5] + t2*Wp[8] + bp[2];
            hout[3*i] = p0; hout[3*i+1] = p1; hout[3*i+2] = p2;
        }
    }
    #pragma unroll
    for (int off = 32; off > 0; off >>= 1) {
        p0 += __shfl_down(p0, off);
        p1 += __shfl_down(p1, off);
        p2 += __shfl_down(p2, off);
    }
    if ((threadIdx.x & 63) == 0) {
        int w = threadIdx.x >> 6;
        ws[w][0] = p0; ws[w][1] = p1; ws[w][2] = p2;
    }
    __syncthreads();
    if (threadIdx.x == 0) {
        pool[3*blockIdx.x]   = ws[0][0] + ws[1][0] + ws[2][0] + ws[3][0];
        pool[3*blockIdx.x+1] = ws[0][1] + ws[1][1] + ws[2][1] + ws[3][1];
        pool[3*blockIdx.x+2] = ws[0][2] + ws[1][2] + ws[2][2] + ws[3][2];
    }
}

__global__ void k_head(const float* __restrict__ pool, int nb,
                       const float* __restrict__ Wl, const float* __restrict__ bl,
                       float* __restrict__ out, int N) {
    __shared__ float sh[12];
    int t = threadIdx.x;
    float p0 = 0.f, p1 = 0.f, p2 = 0.f;
    for (int k = t; k < nb; k += 256) {
        p0 += pool[3*k]; p1 += pool[3*k+1]; p2 += pool[3*k+2];
    }
    #pragma unroll
    for (int off = 32; off > 0; off >>= 1) {
        p0 += __shfl_down(p0, off);
        p1 += __shfl_down(p1, off);
        p2 += __shfl_down(p2, off);
    }
    if ((t & 63) == 0) {
        int w = t >> 6;
        sh[3*w] = p0; sh[3*w+1] = p1; sh[3*w+2] = p2;
    }
    __syncthreads();
    if (t == 0) {
        p0 = sh[0] + sh[3] + sh[6] + sh[9];
        p1 = sh[1] + sh[4] + sh[7] + sh[10];
        p2 = sh[2] + sh[5] + sh[8] + sh[11];
        p0 /= (float)N; p1 /= (float)N; p2 /= (float)N;
        float l[10];
        float m = -1e30f;
        #pragma unroll
        for (int j = 0; j < 10; ++j) {
            l[j] = p0 * Wl[j] + p1 * Wl[10 + j] + p2 * Wl[20 + j] + bl[j];
            m = fmaxf(m, l[j]);
        }
        float s = 0.f;
        #pragma unroll
        for (int j = 0; j < 10; ++j) s += expf(l[j] - m);
        float lse = logf(s) + m;
        #pragma unroll
        for (int j = 0; j < 10; ++j) out[j] = l[j] - lse;
    }
}

extern "C" void kernel_launch(void* const* d_in, const int* in_sizes, int n_in,
                              void* d_out, int out_size, void* d_ws, size_t ws_size,
                              hipStream_t stream) {
    const int N = N_NODES;
    const float* x  = (const float*)d_in[0];
    const int*   ei = (const int*)d_in[1];
    const int    E  = in_sizes[1] / 2;
    const int* src = ei;
    const int* dst = ei + E;
    const float* W1 = (const float*)d_in[2];
    const float* b1 = (const float*)d_in[3];
    const float* W2 = (const float*)d_in[4];
    const float* b2 = (const float*)d_in[5];
    const float* W3 = (const float*)d_in[6];
    const float* b3 = (const float*)d_in[7];
    const float* Wp = (const float*)d_in[8];
    const float* bp = (const float*)d_in[9];
    const float* Wl = (const float*)d_in[10];
    const float* bl = (const float*)d_in[11];

    float* out     = (float*)d_out;
    float* h_out   = out + 10;              // [N,3]
    float* emb_out = out + 10 + 3 * N;      // [N,3]

    char* Wm = (char*)d_ws;
    size_t off = 0;
    auto alloc = [&](size_t elems) { void* p = Wm + off; off += elems * 4; return p; };

    // ---- mega-path layout ----
    int*          col    = (int*)alloc((size_t)E);
    unsigned int* part   = (unsigned int*)alloc((size_t)E);
    int*          hist   = (int*)alloc((size_t)NBK * NP);
    int*          totals = (int*)alloc(NP);
    int*          base   = (int*)alloc(NP + 1);
    int*          offs   = (int*)alloc(N + 1);
    float4*       bufA   = (float4*)alloc(4 * N);
    float4*       bufB   = (float4*)alloc(4 * N);
    float*        pool   = (float*)alloc(3 * NBK);
    int*          bar    = (int*)alloc(16);
    size_t need_mega = off;

    int vec_ok = ((E & 3) == 0) &&
                 ((((uintptr_t)dst) & 15) == 0) &&
                 ((((uintptr_t)src) & 15) == 0);

    if (ws_size >= need_mega) {
        hipMemsetAsync(bar, 0, 16 * sizeof(int), stream);
        k_mega<<<NBK, TPB, 0, stream>>>(src, dst, E, vec_ok, x,
                                        W1, b1, W2, b2, W3, b3, Wp, bp, Wl, bl,
                                        hist, totals, base, offs, part,
                                        bufA, bufB, col, pool, bar,
                                        h_out, emb_out, out, N);
    } else {
        // ---- fallback layout (global-atomic CSR + multi-kernel) ----
        off = 0;
        col  = (int*)alloc((size_t)E);
        int* deg = (int*)alloc(N);
        offs = (int*)alloc(N + 1);
        bufA = (float4*)alloc(4 * N);
        bufB = (float4*)alloc(4 * N);
        int gC = ((size_t)N * G + 255) / 256;
        pool = (float*)alloc(3 * (size_t)gC + 4);
        int* partl = (int*)alloc(1024);
        int* cur = (int*)alloc(N);

        hipMemsetAsync(deg, 0, N * sizeof(int), stream);
        hipMemsetAsync(cur, 0, N * sizeof(int), stream);

        const int B = 256;
        int gE = (E + B - 1) / B;
        int gN = (N + B - 1) / B;

        k_deg<<<gE, B, 0, stream>>>(dst, E, deg);
        k_scan1<<<gN, B, 0, stream>>>(deg, offs, partl, N);
        k_scan2<<<1, 1024, 0, stream>>>(partl, offs, gN, N);
        k_scan3<<<gN, B, 0, stream>>>(offs, partl, N);
        k_fill_cur<<<gE, B, 0, stream>>>(src, dst, offs, cur, col, E);
        k_prescale<<<gN, B, 0, stream>>>(x, offs, bufA, N);

        k_conv1<<<gC, B, 0, stream>>>(offs, col, bufA, W1, b1, W2, bufB, N);
        k_conv2<<<gC, B, 0, stream>>>(offs, col, bufB, b2, W3, emb_out, bufA, N);
        k_conv3<<<gC, B, 0, stream>>>(offs, col, bufA, b3, Wp, bp, h_out, pool, N);
        k_head<<<1, 256, 0, stream>>>(pool, gC, Wl, bl, out, N);
    }
}

// Round 11
// 255.747 us; speedup vs baseline: 2.2435x; 2.2435x over previous
//
#include <hip/hip_runtime.h>
#include <math.h>
#include <stdint.h>

#define N_NODES 100000
#define NB 256          // partition blocks (hist/part)
#define NP 512          // bucket array size (dst >> 8); 391 buckets used
#define BSH 8           // bucket shift
#define BMASK 255u      // node-in-bucket mask
#define NPB 256         // nodes per bucket
#define TC 512          // threads for pre/conv kernels
#define G 8             // fallback conv lanes per node

// ================= bucket-path CSR-less build (no global atomics) =============

__global__ void k_hist(const int* __restrict__ dst, int E, int vec_ok,
                       int* __restrict__ hist) {
    __shared__ int bin[NP];
    if (threadIdx.x < NP) bin[threadIdx.x] = 0;
    __syncthreads();
    if (vec_ok) {
        int ngroups = E >> 2;
        int gchunk = (ngroups + NB - 1) / NB;
        int gbeg = blockIdx.x * gchunk;
        int gend = gbeg + gchunk; if (gend > ngroups) gend = ngroups;
        const int4* d4 = (const int4*)dst;
        for (int g = gbeg + threadIdx.x; g < gend; g += 1024) {
            int4 d = d4[g];
            atomicAdd(&bin[d.x >> BSH], 1);
            atomicAdd(&bin[d.y >> BSH], 1);
            atomicAdd(&bin[d.z >> BSH], 1);
            atomicAdd(&bin[d.w >> BSH], 1);
        }
        if (blockIdx.x == 0) {
            for (int e = (ngroups << 2) + threadIdx.x; e < E; e += 1024)
                atomicAdd(&bin[dst[e] >> BSH], 1);
        }
    } else {
        int echunk = (E + NB - 1) / NB;
        int ebeg = blockIdx.x * echunk;
        int eend = ebeg + echunk; if (eend > E) eend = E;
        for (int e = ebeg + threadIdx.x; e < eend; e += 1024)
            atomicAdd(&bin[dst[e] >> BSH], 1);
    }
    __syncthreads();
    if (threadIdx.x < NP)
        hist[blockIdx.x * NP + threadIdx.x] = bin[threadIdx.x];
}

// bucket totals + exclusive scan -> base[0..NP], base[NP]=E   (1 block x NP)
__global__ void k_s1(const int* __restrict__ hist, int* __restrict__ base, int E) {
    __shared__ int sh[NP];
    int b = threadIdx.x;
    int s = 0;
    #pragma unroll 8
    for (int k = 0; k < NB; ++k) s += hist[k * NP + b];
    sh[b] = s;
    __syncthreads();
    for (int off = 1; off < NP; off <<= 1) {
        int u = (b >= off) ? sh[b - off] : 0;
        __syncthreads();
        sh[b] += u;
        __syncthreads();
    }
    base[b] = sh[b] - s;
    if (b == NP - 1) base[NP] = E;
}

// per-bucket scan over block counts: hist[k][b] := base[b] + sum_{k'<k} hist[k'][b]
__global__ void k_s2(int* __restrict__ hist, const int* __restrict__ base) {
    __shared__ int sh[NB];
    int b = blockIdx.x, t = threadIdx.x;
    int v = hist[t * NP + b];
    sh[t] = v;
    __syncthreads();
    for (int off = 1; off < NB; off <<= 1) {
        int u = (t >= off) ? sh[t - off] : 0;
        __syncthreads();
        sh[t] += u;
        __syncthreads();
    }
    hist[t * NP + b] = base[b] + sh[t] - v;
}

// partition edges into bucket-grouped part[]: value = (src<<BSH) | (dst&BMASK)
__global__ void k_part(const int* __restrict__ src, const int* __restrict__ dst,
                       int E, int vec_ok, const int* __restrict__ hist,
                       unsigned int* __restrict__ part) {
    __shared__ int cur[NP];
    if (threadIdx.x < NP)
        cur[threadIdx.x] = hist[blockIdx.x * NP + threadIdx.x];
    __syncthreads();
    if (vec_ok) {
        int ngroups = E >> 2;
        int gchunk = (ngroups + NB - 1) / NB;
        int gbeg = blockIdx.x * gchunk;
        int gend = gbeg + gchunk; if (gend > ngroups) gend = ngroups;
        const int4* d4 = (const int4*)dst;
        const int4* s4 = (const int4*)src;
        for (int g = gbeg + threadIdx.x; g < gend; g += 1024) {
            int4 d = d4[g];
            int4 s = s4[g];
            int p;
            p = atomicAdd(&cur[d.x >> BSH], 1);
            part[p] = ((unsigned)s.x << BSH) | ((unsigned)d.x & BMASK);
            p = atomicAdd(&cur[d.y >> BSH], 1);
            part[p] = ((unsigned)s.y << BSH) | ((unsigned)d.y & BMASK);
            p = atomicAdd(&cur[d.z >> BSH], 1);
            part[p] = ((unsigned)s.z << BSH) | ((unsigned)d.z & BMASK);
            p = atomicAdd(&cur[d.w >> BSH], 1);
            part[p] = ((unsigned)s.w << BSH) | ((unsigned)d.w & BMASK);
        }
        if (blockIdx.x == 0) {
            for (int e = (ngroups << 2) + threadIdx.x; e < E; e += 1024) {
                int d = dst[e];
                int p = atomicAdd(&cur[d >> BSH], 1);
                part[p] = ((unsigned)src[e] << BSH) | ((unsigned)d & BMASK);
            }
        }
    } else {
        int echunk = (E + NB - 1) / NB;
        int ebeg = blockIdx.x * echunk;
        int eend = ebeg + echunk; if (eend > E) eend = E;
        for (int e = ebeg + threadIdx.x; e < eend; e += 1024) {
            int d = dst[e];
            int p = atomicAdd(&cur[d >> BSH], 1);
            part[p] = ((unsigned)src[e] << BSH) | ((unsigned)d & BMASK);
        }
    }
}

// per-bucket degree count -> dinv + prescaled xp4 (w = dinv). No CSR scatter.
__global__ __launch_bounds__(TC) void k_pre(const unsigned int* __restrict__ part,
                                            const int* __restrict__ base,
                                            const float* __restrict__ x,
                                            float4* __restrict__ xp4, int N) {
    __shared__ int cnt[NPB];
    int b = blockIdx.x, t = threadIdx.x;
    if (t < NPB) cnt[t] = 0;
    __syncthreads();
    int lo = base[b], hi = base[b + 1];
    for (int e = lo + t; e < hi; e += TC)
        atomicAdd(&cnt[part[e] & BMASK], 1);
    __syncthreads();
    if (t < NPB) {
        int node = (b << BSH) + t;
        if (node < N) {
            float di = rsqrtf((float)(cnt[t] + 1));   // +1 self-loop
            xp4[node] = make_float4(x[3*node] * di, x[3*node+1] * di,
                                    x[3*node+2] * di, di);
        }
    }
}

// ============ edge-parallel LDS-scatter conv core (one block per bucket) ======

#define ACC3(w, f, v) atomicAdd(&acc[3*((w) & BMASK) + (f)], (v))

__device__ __forceinline__ void bucket_accum(const unsigned int* __restrict__ part,
                                             const float4* __restrict__ tab,
                                             float* acc, int lo, int hi, int t) {
    int e = lo + t;
    for (; e + 7*TC < hi; e += 8*TC) {
        unsigned w0 = part[e],      w1 = part[e+TC],   w2 = part[e+2*TC], w3 = part[e+3*TC];
        unsigned w4 = part[e+4*TC], w5 = part[e+5*TC], w6 = part[e+6*TC], w7 = part[e+7*TC];
        float4 v0 = tab[w0 >> BSH], v1 = tab[w1 >> BSH], v2 = tab[w2 >> BSH], v3 = tab[w3 >> BSH];
        float4 v4 = tab[w4 >> BSH], v5 = tab[w5 >> BSH], v6 = tab[w6 >> BSH], v7 = tab[w7 >> BSH];
        ACC3(w0,0,v0.x); ACC3(w0,1,v0.y); ACC3(w0,2,v0.z);
        ACC3(w1,0,v1.x); ACC3(w1,1,v1.y); ACC3(w1,2,v1.z);
        ACC3(w2,0,v2.x); ACC3(w2,1,v2.y); ACC3(w2,2,v2.z);
        ACC3(w3,0,v3.x); ACC3(w3,1,v3.y); ACC3(w3,2,v3.z);
        ACC3(w4,0,v4.x); ACC3(w4,1,v4.y); ACC3(w4,2,v4.z);
        ACC3(w5,0,v5.x); ACC3(w5,1,v5.y); ACC3(w5,2,v5.z);
        ACC3(w6,0,v6.x); ACC3(w6,1,v6.y); ACC3(w6,2,v6.z);
        ACC3(w7,0,v7.x); ACC3(w7,1,v7.y); ACC3(w7,2,v7.z);
    }
    for (; e < hi; e += TC) {
        unsigned w = part[e];
        float4 v = tab[w >> BSH];
        ACC3(w,0,v.x); ACC3(w,1,v.y); ACC3(w,2,v.z);
    }
}

__global__ __launch_bounds__(TC) void k_sc1(const unsigned int* __restrict__ part,
        const int* __restrict__ base, const float4* __restrict__ xp4,
        const float* __restrict__ W1, const float* __restrict__ b1,
        const float* __restrict__ W2, float4* __restrict__ h2p4, int N) {
    __shared__ float acc[NPB * 3];
    int b = blockIdx.x, t = threadIdx.x;
    int node = (b << BSH) + t;
    float4 self = make_float4(0.f, 0.f, 0.f, 0.f);
    if (t < NPB) {
        if (node < N) self = xp4[node];
        acc[3*t] = self.x; acc[3*t+1] = self.y; acc[3*t+2] = self.z;
    }
    __syncthreads();
    bucket_accum(part, xp4, acc, base[b], base[b+1], t);
    __syncthreads();
    if (t < NPB && node < N) {
        float di = self.w;
        float g0 = acc[3*t] * di, g1 = acc[3*t+1] * di, g2 = acc[3*t+2] * di;
        float o0 = 0.f, o1 = 0.f, o2 = 0.f;
        #pragma unroll
        for (int j = 0; j < 16; ++j) {
            float tv = fmaxf(g0 * W1[j] + g1 * W1[16 + j] + g2 * W1[32 + j] + b1[j], 0.f);
            o0 += tv * W2[3*j + 0];
            o1 += tv * W2[3*j + 1];
            o2 += tv * W2[3*j + 2];
        }
        h2p4[node] = make_float4(o0 * di, o1 * di, o2 * di, di);
    }
}

__global__ __launch_bounds__(TC) void k_sc2(const unsigned int* __restrict__ part,
        const int* __restrict__ base, const float4* __restrict__ h2p4,
        const float* __restrict__ b2, const float* __restrict__ W3,
        float* __restrict__ embed_out, float4* __restrict__ h3p4, int N) {
    __shared__ float acc[NPB * 3];
    int b = blockIdx.x, t = threadIdx.x;
    int node = (b << BSH) + t;
    float4 self = make_float4(0.f, 0.f, 0.f, 0.f);
    if (t < NPB) {
        if (node < N) self = h2p4[node];
        acc[3*t] = self.x; acc[3*t+1] = self.y; acc[3*t+2] = self.z;
    }
    __syncthreads();
    bucket_accum(part, h2p4, acc, base[b], base[b+1], t);
    __syncthreads();
    if (t < NPB && node < N) {
        float di = self.w;
        float t0 = acc[3*t]   * di + b2[0];
        float t1 = acc[3*t+1] * di + b2[1];
        float t2 = acc[3*t+2] * di + b2[2];
        float inv = 1.0f / fmaxf(sqrtf(t0*t0 + t1*t1 + t2*t2), 1e-12f);
        float e0 = t0*inv, e1 = t1*inv, e2 = t2*inv;
        embed_out[3*node] = e0; embed_out[3*node+1] = e1; embed_out[3*node+2] = e2;
        h3p4[node] = make_float4((e0*W3[0] + e1*W3[3] + e2*W3[6]) * di,
                                 (e0*W3[1] + e1*W3[4] + e2*W3[7]) * di,
                                 (e0*W3[2] + e1*W3[5] + e2*W3[8]) * di, di);
    }
}

__global__ __launch_bounds__(TC) void k_sc3(const unsigned int* __restrict__ part,
        const int* __restrict__ base, const float4* __restrict__ h3p4,
        const float* __restrict__ b3, const float* __restrict__ Wp,
        const float* __restrict__ bp,
        float* __restrict__ hout, float* __restrict__ pool, int N) {
    __shared__ float acc[NPB * 3];
    __shared__ float wsum[TC/64][3];
    int b = blockIdx.x, t = threadIdx.x;
    int node = (b << BSH) + t;
    float4 self = make_float4(0.f, 0.f, 0.f, 0.f);
    if (t < NPB) {
        if (node < N) self = h3p4[node];
        acc[3*t] = self.x; acc[3*t+1] = self.y; acc[3*t+2] = self.z;
    }
    __syncthreads();
    bucket_accum(part, h3p4, acc, base[b], base[b+1], t);
    __syncthreads();
    float q0 = 0.f, q1 = 0.f, q2 = 0.f;
    if (t < NPB && node < N) {
        float di = self.w;
        float t0 = acc[3*t]   * di + b3[0];
        float t1 = acc[3*t+1] * di + b3[1];
        float t2 = acc[3*t+2] * di + b3[2];
        q0 = t0*Wp[0] + t1*Wp[3] + t2*Wp[6] + bp[0];
        q1 = t0*Wp[1] + t1*Wp[4] + t2*Wp[7] + bp[1];
        q2 = t0*Wp[2] + t1*Wp[5] + t2*Wp[8] + bp[2];
        hout[3*node] = q0; hout[3*node+1] = q1; hout[3*node+2] = q2;
    }
    #pragma unroll
    for (int off = 32; off > 0; off >>= 1) {
        q0 += __shfl_down(q0, off);
        q1 += __shfl_down(q1, off);
        q2 += __shfl_down(q2, off);
    }
    if ((t & 63) == 0) {
        int w = t >> 6;
        wsum[w][0] = q0; wsum[w][1] = q1; wsum[w][2] = q2;
    }
    __syncthreads();
    if (t == 0) {
        float a0 = 0.f, a1 = 0.f, a2 = 0.f;
        #pragma unroll
        for (int w = 0; w < TC/64; ++w) {
            a0 += wsum[w][0]; a1 += wsum[w][1]; a2 += wsum[w][2];
        }
        pool[3*b] = a0; pool[3*b+1] = a1; pool[3*b+2] = a2;
    }
}

// head: deterministic reduce of block partials, then logits + log_softmax
__global__ void k_head(const float* __restrict__ pool, int nb,
                       const float* __restrict__ Wl, const float* __restrict__ bl,
                       float* __restrict__ out, int N) {
    __shared__ float sh[12];
    int t = threadIdx.x;
    float p0 = 0.f, p1 = 0.f, p2 = 0.f;
    for (int k = t; k < nb; k += 256) {
        p0 += pool[3*k]; p1 += pool[3*k+1]; p2 += pool[3*k+2];
    }
    #pragma unroll
    for (int off = 32; off > 0; off >>= 1) {
        p0 += __shfl_down(p0, off);
        p1 += __shfl_down(p1, off);
        p2 += __shfl_down(p2, off);
    }
    if ((t & 63) == 0) {
        int w = t >> 6;
        sh[3*w] = p0; sh[3*w+1] = p1; sh[3*w+2] = p2;
    }
    __syncthreads();
    if (t == 0) {
        p0 = sh[0] + sh[3] + sh[6] + sh[9];
        p1 = sh[1] + sh[4] + sh[7] + sh[10];
        p2 = sh[2] + sh[5] + sh[8] + sh[11];
        p0 /= (float)N; p1 /= (float)N; p2 /= (float)N;
        float l[10];
        float m = -1e30f;
        #pragma unroll
        for (int j = 0; j < 10; ++j) {
            l[j] = p0 * Wl[j] + p1 * Wl[10 + j] + p2 * Wl[20 + j] + bl[j];
            m = fmaxf(m, l[j]);
        }
        float s = 0.f;
        #pragma unroll
        for (int j = 0; j < 10; ++j) s += expf(l[j] - m);
        float lse = logf(s) + m;
        #pragma unroll
        for (int j = 0; j < 10; ++j) out[j] = l[j] - lse;
    }
}

// ================= fallback pipeline (global atomics, CSR) ==========

__global__ void k_deg(const int* __restrict__ dst, int E, int* __restrict__ deg) {
    int e = blockIdx.x * blockDim.x + threadIdx.x;
    if (e < E) atomicAdd(&deg[dst[e]], 1);
}

__global__ void k_scan1(const int* __restrict__ deg, int* __restrict__ offs,
                        int* __restrict__ partl, int N) {
    __shared__ int sh[256];
    int i = blockIdx.x * 256 + threadIdx.x;
    int t = threadIdx.x;
    int v = (i < N) ? deg[i] : 0;
    sh[t] = v;
    __syncthreads();
    #pragma unroll
    for (int off = 1; off < 256; off <<= 1) {
        int u = (t >= off) ? sh[t - off] : 0;
        __syncthreads();
        sh[t] += u;
        __syncthreads();
    }
    if (i < N) offs[i] = sh[t] - v;
    if (t == 255) partl[blockIdx.x] = sh[255];
}

__global__ void k_scan2(int* __restrict__ partl, int* __restrict__ offs, int nb, int N) {
    __shared__ int sh[1024];
    int t = threadIdx.x;
    int v = (t < nb) ? partl[t] : 0;
    sh[t] = v;
    __syncthreads();
    #pragma unroll
    for (int off = 1; off < 1024; off <<= 1) {
        int u = (t >= off) ? sh[t - off] : 0;
        __syncthreads();
        sh[t] += u;
        __syncthreads();
    }
    if (t < nb) partl[t] = sh[t] - v;
    if (t == 1023) offs[N] = sh[1023];
}

__global__ void k_scan3(int* __restrict__ offs, const int* __restrict__ partl, int N) {
    int i = blockIdx.x * 256 + threadIdx.x;
    if (i < N) offs[i] += partl[blockIdx.x];
}

__global__ void k_fill_cur(const int* __restrict__ src, const int* __restrict__ dst,
                           const int* __restrict__ offs, int* __restrict__ cur,
                           int* __restrict__ col, int E) {
    int e = blockIdx.x * blockDim.x + threadIdx.x;
    if (e >= E) return;
    int d = dst[e];
    col[offs[d] + atomicAdd(&cur[d], 1)] = src[e];
}

__global__ void k_prescale(const float* __restrict__ x, const int* __restrict__ offs,
                           float4* __restrict__ xp4, int N) {
    int i = blockIdx.x * blockDim.x + threadIdx.x;
    if (i >= N) return;
    int d = offs[i+1] - offs[i];
    float di = rsqrtf((float)(d + 1));
    xp4[i] = make_float4(x[3*i] * di, x[3*i+1] * di, x[3*i+2] * di, di);
}

__device__ __forceinline__ void gather_sum(const int* __restrict__ col,
                                           const float4* __restrict__ tab,
                                           int beg, int end, int g,
                                           float& s0, float& s1, float& s2) {
    int k = beg + g;
    for (; k + 3*G < end; k += 4*G) {
        int c0 = col[k], c1 = col[k+G], c2 = col[k+2*G], c3 = col[k+3*G];
        float4 v0 = tab[c0], v1 = tab[c1], v2 = tab[c2], v3 = tab[c3];
        s0 += v0.x; s1 += v0.y; s2 += v0.z;
        s0 += v1.x; s1 += v1.y; s2 += v1.z;
        s0 += v2.x; s1 += v2.y; s2 += v2.z;
        s0 += v3.x; s1 += v3.y; s2 += v3.z;
    }
    for (; k < end; k += G) {
        float4 v = tab[col[k]];
        s0 += v.x; s1 += v.y; s2 += v.z;
    }
}

__global__ void k_conv1(const int* __restrict__ offs, const int* __restrict__ col,
                        const float4* __restrict__ xp4,
                        const float* __restrict__ W1, const float* __restrict__ b1,
                        const float* __restrict__ W2,
                        float4* __restrict__ h2p4, int N) {
    int tid = blockIdx.x * blockDim.x + threadIdx.x;
    int i = tid >> 3, g = tid & (G - 1);
    if (i >= N) return;
    float s0 = 0.f, s1 = 0.f, s2 = 0.f, di = 0.f;
    if (g == 0) {
        float4 self = xp4[i];
        s0 = self.x; s1 = self.y; s2 = self.z; di = self.w;
    }
    gather_sum(col, xp4, offs[i], offs[i+1], g, s0, s1, s2);
    #pragma unroll
    for (int off = G/2; off > 0; off >>= 1) {
        s0 += __shfl_down(s0, off, G);
        s1 += __shfl_down(s1, off, G);
        s2 += __shfl_down(s2, off, G);
    }
    if (g == 0) {
        float g0 = s0 * di, g1 = s1 * di, g2 = s2 * di;
        float o0 = 0.f, o1 = 0.f, o2 = 0.f;
        #pragma unroll
        for (int j = 0; j < 16; ++j) {
            float t = fmaxf(g0 * W1[j] + g1 * W1[16 + j] + g2 * W1[32 + j] + b1[j], 0.f);
            o0 += t * W2[3*j + 0];
            o1 += t * W2[3*j + 1];
            o2 += t * W2[3*j + 2];
        }
        h2p4[i] = make_float4(o0 * di, o1 * di, o2 * di, di);
    }
}

__global__ void k_conv2(const int* __restrict__ offs, const int* __restrict__ col,
                        const float4* __restrict__ h2p4,
                        const float* __restrict__ b2, const float* __restrict__ W3,
                        float* __restrict__ embed_out, float4* __restrict__ h3p4, int N) {
    int tid = blockIdx.x * blockDim.x + threadIdx.x;
    int i = tid >> 3, g = tid & (G - 1);
    if (i >= N) return;
    float s0 = 0.f, s1 = 0.f, s2 = 0.f, di = 0.f;
    if (g == 0) {
        float4 self = h2p4[i];
        s0 = self.x; s1 = self.y; s2 = self.z; di = self.w;
    }
    gather_sum(col, h2p4, offs[i], offs[i+1], g, s0, s1, s2);
    #pragma unroll
    for (int off = G/2; off > 0; off >>= 1) {
        s0 += __shfl_down(s0, off, G);
        s1 += __shfl_down(s1, off, G);
        s2 += __shfl_down(s2, off, G);
    }
    if (g == 0) {
        float t0 = s0 * di + b2[0];
        float t1 = s1 * di + b2[1];
        float t2 = s2 * di + b2[2];
        float inv = 1.0f / fmaxf(sqrtf(t0*t0 + t1*t1 + t2*t2), 1e-12f);
        float e0 = t0*inv, e1 = t1*inv, e2 = t2*inv;
        embed_out[3*i] = e0; embed_out[3*i+1] = e1; embed_out[3*i+2] = e2;
        h3p4[i] = make_float4((e0*W3[0] + e1*W3[3] + e2*W3[6]) * di,
                              (e0*W3[1] + e1*W3[4] + e2*W3[7]) * di,
                              (e0*W3[2] + e1*W3[5] + e2*W3[8]) * di, di);
    }
}

__global__ void k_conv3(const int* __restrict__ offs, const int* __restrict__ col,
                        const float4* __restrict__ h3p4,
                        const float* __restrict__ b3, const float* __restrict__ Wp,
                        const float* __restrict__ bp,
                        float* __restrict__ hout, float* __restrict__ pool, int N) {
    __shared__ float ws[4][3];
    int tid = blockIdx.x * blockDim.x + threadIdx.x;
    int i = tid >> 3, g = tid & (G - 1);
    float p0 = 0.f, p1 = 0.f, p2 = 0.f;
    if (i < N) {
        float s0 = 0.f, s1 = 0.f, s2 = 0.f, di = 0.f;
        if (g == 0) {
            float4 self = h3p4[i];
            s0 = self.x; s1 = self.y; s2 = self.z; di = self.w;
        }
        gather_sum(col, h3p4, offs[i], offs[i+1], g, s0, s1, s2);
        #pragma unroll
        for (int off = G/2; off > 0; off >>= 1) {
            s0 += __shfl_down(s0, off, G);
            s1 += __shfl_down(s1, off, G);
            s2 += __shfl_down(s2, off, G);
        }
        if (g == 0) {
            float t0 = s0 * di + b3[0];
            float t1 = s1 * di + b3[1];
            float t2 = s2 * di + b3[2];
            p0 = t0*Wp[0] + t1*Wp[3] + t2*Wp[6] + bp[0];
            p1 = t0*Wp[1] + t1*Wp[4] + t2*Wp[7] + bp[1];
            p2 = t0*Wp[2] + t1*Wp[5] + t2*Wp[8] + bp[2];
            hout[3*i] = p0; hout[3*i+1] = p1; hout[3*i+2] = p2;
        }
    }
    #pragma unroll
    for (int off = 32; off > 0; off >>= 1) {
        p0 += __shfl_down(p0, off);
        p1 += __shfl_down(p1, off);
        p2 += __shfl_down(p2, off);
    }
    if ((threadIdx.x & 63) == 0) {
        int w = threadIdx.x >> 6;
        ws[w][0] = p0; ws[w][1] = p1; ws[w][2] = p2;
    }
    __syncthreads();
    if (threadIdx.x == 0) {
        pool[3*blockIdx.x]   = ws[0][0] + ws[1][0] + ws[2][0] + ws[3][0];
        pool[3*blockIdx.x+1] = ws[0][1] + ws[1][1] + ws[2][1] + ws[3][1];
        pool[3*blockIdx.x+2] = ws[0][2] + ws[1][2] + ws[2][2] + ws[3][2];
    }
}

extern "C" void kernel_launch(void* const* d_in, const int* in_sizes, int n_in,
                              void* d_out, int out_size, void* d_ws, size_t ws_size,
                              hipStream_t stream) {
    const int N = N_NODES;
    const float* x  = (const float*)d_in[0];
    const int*   ei = (const int*)d_in[1];
    const int    E  = in_sizes[1] / 2;
    const int* src = ei;
    const int* dst = ei + E;
    const float* W1 = (const float*)d_in[2];
    const float* b1 = (const float*)d_in[3];
    const float* W2 = (const float*)d_in[4];
    const float* b2 = (const float*)d_in[5];
    const float* W3 = (const float*)d_in[6];
    const float* b3 = (const float*)d_in[7];
    const float* Wp = (const float*)d_in[8];
    const float* bp = (const float*)d_in[9];
    const float* Wl = (const float*)d_in[10];
    const float* bl = (const float*)d_in[11];

    float* out     = (float*)d_out;
    float* h_out   = out + 10;              // [N,3]
    float* emb_out = out + 10 + 3 * N;      // [N,3]

    const int NBUCK = (N + NPB - 1) >> BSH; // 391 buckets

    char* Wm = (char*)d_ws;
    size_t off = 0;
    auto alloc = [&](size_t elems) { void* p = Wm + off; off += elems * 4; return p; };

    // ---- bucket-path layout ----
    unsigned int* part = (unsigned int*)alloc((size_t)E);
    int*          hist = (int*)alloc((size_t)NB * NP);
    int*          base = (int*)alloc(NP + 1);
    float4*       bufA = (float4*)alloc(4 * N);
    float4*       bufB = (float4*)alloc(4 * N);
    float*        pool = (float*)alloc(3 * NP + 4);
    size_t need_bucket = off;

    int vec_ok = ((E & 3) == 0) &&
                 ((((uintptr_t)dst) & 15) == 0) &&
                 ((((uintptr_t)src) & 15) == 0);

    if (ws_size >= need_bucket) {
        k_hist<<<NB, 1024, 0, stream>>>(dst, E, vec_ok, hist);
        k_s1<<<1, NP, 0, stream>>>(hist, base, E);
        k_s2<<<NP, NB, 0, stream>>>(hist, base);
        k_part<<<NB, 1024, 0, stream>>>(src, dst, E, vec_ok, hist, part);
        k_pre<<<NBUCK, TC, 0, stream>>>(part, base, x, bufA, N);

        k_sc1<<<NBUCK, TC, 0, stream>>>(part, base, bufA, W1, b1, W2, bufB, N);
        k_sc2<<<NBUCK, TC, 0, stream>>>(part, base, bufB, b2, W3, emb_out, bufA, N);
        k_sc3<<<NBUCK, TC, 0, stream>>>(part, base, bufA, b3, Wp, bp, h_out, pool, N);

        k_head<<<1, 256, 0, stream>>>(pool, NBUCK, Wl, bl, out, N);
    } else {
        // ---- fallback layout (global-atomic CSR + node-parallel convs) ----
        off = 0;
        int*    col  = (int*)alloc((size_t)E);
        int*    deg  = (int*)alloc(N);
        int*    offs = (int*)alloc(N + 1);
        float4* fA   = (float4*)alloc(4 * N);
        float4* fB   = (float4*)alloc(4 * N);
        int gC = ((size_t)N * G + 255) / 256;
        float*  fpool = (float*)alloc(3 * (size_t)gC + 4);
        int*    partl = (int*)alloc(1024);
        int*    cur   = (int*)alloc(N);

        hipMemsetAsync(deg, 0, N * sizeof(int), stream);
        hipMemsetAsync(cur, 0, N * sizeof(int), stream);

        const int B = 256;
        int gE = (E + B - 1) / B;
        int gN = (N + B - 1) / B;

        k_deg<<<gE, B, 0, stream>>>(dst, E, deg);
        k_scan1<<<gN, B, 0, stream>>>(deg, offs, partl, N);
        k_scan2<<<1, 1024, 0, stream>>>(partl, offs, gN, N);
        k_scan3<<<gN, B, 0, stream>>>(offs, partl, N);
        k_fill_cur<<<gE, B, 0, stream>>>(src, dst, offs, cur, col, E);
        k_prescale<<<gN, B, 0, stream>>>(x, offs, fA, N);

        k_conv1<<<gC, B, 0, stream>>>(offs, col, fA, W1, b1, W2, fB, N);
        k_conv2<<<gC, B, 0, stream>>>(offs, col, fB, b2, W3, emb_out, fA, N);
        k_conv3<<<gC, B, 0, stream>>>(offs, col, fA, b3, Wp, bp, h_out, fpool, N);
        k_head<<<1, 256, 0, stream>>>(fpool, gC, Wl, bl, out, N);
    }
}

// Round 13
// 200.417 us; speedup vs baseline: 2.8629x; 1.2761x over previous
//
#include <hip/hip_runtime.h>
#include <math.h>
#include <stdint.h>

#define N_NODES 100000
#define NB 512          // partition blocks (hist/part)
#define TPP 512         // threads for hist/part
#define NP 256          // buckets (dst >> 9), 512 nodes per bucket
#define BSH 9           // bucket shift
#define BMASK 511u      // node-in-bucket mask
#define G 8             // lanes per node in conv gathers

// ================= bucket-path CSR build (no global atomics) =================

__global__ void k_hist(const int* __restrict__ dst, int E, int vec_ok,
                       int* __restrict__ hist) {
    __shared__ int bin[NP];
    if (threadIdx.x < NP) bin[threadIdx.x] = 0;
    __syncthreads();
    if (vec_ok) {
        int ngroups = E >> 2;
        int gchunk = (ngroups + NB - 1) / NB;
        int gbeg = blockIdx.x * gchunk;
        int gend = gbeg + gchunk; if (gend > ngroups) gend = ngroups;
        const int4* d4 = (const int4*)dst;
        for (int g = gbeg + threadIdx.x; g < gend; g += TPP) {
            int4 d = d4[g];
            atomicAdd(&bin[d.x >> BSH], 1);
            atomicAdd(&bin[d.y >> BSH], 1);
            atomicAdd(&bin[d.z >> BSH], 1);
            atomicAdd(&bin[d.w >> BSH], 1);
        }
        if (blockIdx.x == 0) {
            for (int e = (ngroups << 2) + threadIdx.x; e < E; e += TPP)
                atomicAdd(&bin[dst[e] >> BSH], 1);
        }
    } else {
        int echunk = (E + NB - 1) / NB;
        int ebeg = blockIdx.x * echunk;
        int eend = ebeg + echunk; if (eend > E) eend = E;
        for (int e = ebeg + threadIdx.x; e < eend; e += TPP)
            atomicAdd(&bin[dst[e] >> BSH], 1);
    }
    __syncthreads();
    if (threadIdx.x < NP)
        hist[blockIdx.x * NP + threadIdx.x] = bin[threadIdx.x];
}

// bucket totals + exclusive scan -> base[0..NP], base[NP]=E   (1 block x NP)
__global__ void k_s1(const int* __restrict__ hist, int* __restrict__ base, int E) {
    __shared__ int sh[NP];
    int b = threadIdx.x;
    int s = 0;
    #pragma unroll 8
    for (int k = 0; k < NB; ++k) s += hist[k * NP + b];
    sh[b] = s;
    __syncthreads();
    for (int off = 1; off < NP; off <<= 1) {
        int u = (b >= off) ? sh[b - off] : 0;
        __syncthreads();
        sh[b] += u;
        __syncthreads();
    }
    base[b] = sh[b] - s;
    if (b == NP - 1) base[NP] = E;
}

// per-bucket scan over block counts: hist[k][b] := base[b] + sum_{k'<k} hist[k'][b]
__global__ void k_s2(int* __restrict__ hist, const int* __restrict__ base) {
    __shared__ int sh[NB];
    int b = blockIdx.x, t = threadIdx.x;   // t == partition-block index k
    int v = hist[t * NP + b];
    sh[t] = v;
    __syncthreads();
    for (int off = 1; off < NB; off <<= 1) {
        int u = (t >= off) ? sh[t - off] : 0;
        __syncthreads();
        sh[t] += u;
        __syncthreads();
    }
    hist[t * NP + b] = base[b] + sh[t] - v;
}

// partition edges into bucket-grouped part[]: value = (src<<BSH) | (dst&BMASK)
__global__ void k_part(const int* __restrict__ src, const int* __restrict__ dst,
                       int E, int vec_ok, const int* __restrict__ hist,
                       unsigned int* __restrict__ part) {
    __shared__ int cur[NP];
    if (threadIdx.x < NP)
        cur[threadIdx.x] = hist[blockIdx.x * NP + threadIdx.x];
    __syncthreads();
    if (vec_ok) {
        int ngroups = E >> 2;
        int gchunk = (ngroups + NB - 1) / NB;
        int gbeg = blockIdx.x * gchunk;
        int gend = gbeg + gchunk; if (gend > ngroups) gend = ngroups;
        const int4* d4 = (const int4*)dst;
        const int4* s4 = (const int4*)src;
        for (int g = gbeg + threadIdx.x; g < gend; g += TPP) {
            int4 d = d4[g];
            int4 s = s4[g];
            int p;
            p = atomicAdd(&cur[d.x >> BSH], 1);
            part[p] = ((unsigned)s.x << BSH) | ((unsigned)d.x & BMASK);
            p = atomicAdd(&cur[d.y >> BSH], 1);
            part[p] = ((unsigned)s.y << BSH) | ((unsigned)d.y & BMASK);
            p = atomicAdd(&cur[d.z >> BSH], 1);
            part[p] = ((unsigned)s.z << BSH) | ((unsigned)d.z & BMASK);
            p = atomicAdd(&cur[d.w >> BSH], 1);
            part[p] = ((unsigned)s.w << BSH) | ((unsigned)d.w & BMASK);
        }
        if (blockIdx.x == 0) {
            for (int e = (ngroups << 2) + threadIdx.x; e < E; e += TPP) {
                int d = dst[e];
                int p = atomicAdd(&cur[d >> BSH], 1);
                part[p] = ((unsigned)src[e] << BSH) | ((unsigned)d & BMASK);
            }
        }
    } else {
        int echunk = (E + NB - 1) / NB;
        int ebeg = blockIdx.x * echunk;
        int eend = ebeg + echunk; if (eend > E) eend = E;
        for (int e = ebeg + threadIdx.x; e < eend; e += TPP) {
            int d = dst[e];
            int p = atomicAdd(&cur[d >> BSH], 1);
            part[p] = ((unsigned)src[e] << BSH) | ((unsigned)d & BMASK);
        }
    }
}

// per-bucket (1024 threads): deg -> offs; prescaled xp4 (w = dinv); scatter col
__global__ void k_csr(const unsigned int* __restrict__ part, const int* __restrict__ base,
                      const float* __restrict__ x,
                      int* __restrict__ offs,
                      float4* __restrict__ xp4, int* __restrict__ col, int N) {
    __shared__ int cnt[512];
    __shared__ int scn[512];
    __shared__ int cur[512];
    int b = blockIdx.x, t = threadIdx.x;
    int lo = base[b], hi = base[b + 1];
    if (t < 512) cnt[t] = 0;
    __syncthreads();
    for (int e = lo + t; e < hi; e += 1024)
        atomicAdd(&cnt[part[e] & BMASK], 1);
    __syncthreads();
    int v = (t < 512) ? cnt[t] : 0;
    if (t < 512) scn[t] = v;
    __syncthreads();
    for (int off = 1; off < 512; off <<= 1) {
        int u = (t < 512 && t >= off) ? scn[t - off] : 0;
        __syncthreads();
        if (t < 512) scn[t] += u;
        __syncthreads();
    }
    if (t < 512) {
        int pos = lo + scn[t] - v;        // exclusive
        cur[t] = pos;
        int g = (b << BSH) + t;
        if (g < N) {
            offs[g] = pos;
            float di = rsqrtf((float)(v + 1));   // +1 self-loop
            xp4[g] = make_float4(x[3*g] * di, x[3*g+1] * di, x[3*g+2] * di, di);
        }
    }
    if (b == 0 && t == 0) offs[N] = base[(N_NODES + 511) >> BSH];
    __syncthreads();
    for (int e = lo + t; e < hi; e += 1024) {
        unsigned int w = part[e];
        int p = atomicAdd(&cur[w & BMASK], 1);
        col[p] = (int)(w >> BSH);
    }
}

// ================= fallback CSR build (global atomics) ==========

__global__ void k_deg(const int* __restrict__ dst, int E, int* __restrict__ deg) {
    int e = blockIdx.x * blockDim.x + threadIdx.x;
    if (e < E) atomicAdd(&deg[dst[e]], 1);
}

__global__ void k_scan1(const int* __restrict__ deg, int* __restrict__ offs,
                        int* __restrict__ partl, int N) {
    __shared__ int sh[256];
    int i = blockIdx.x * 256 + threadIdx.x;
    int t = threadIdx.x;
    int v = (i < N) ? deg[i] : 0;
    sh[t] = v;
    __syncthreads();
    #pragma unroll
    for (int off = 1; off < 256; off <<= 1) {
        int u = (t >= off) ? sh[t - off] : 0;
        __syncthreads();
        sh[t] += u;
        __syncthreads();
    }
    if (i < N) offs[i] = sh[t] - v;
    if (t == 255) partl[blockIdx.x] = sh[255];
}

__global__ void k_scan2(int* __restrict__ partl, int* __restrict__ offs, int nb, int N) {
    __shared__ int sh[1024];
    int t = threadIdx.x;
    int v = (t < nb) ? partl[t] : 0;
    sh[t] = v;
    __syncthreads();
    #pragma unroll
    for (int off = 1; off < 1024; off <<= 1) {
        int u = (t >= off) ? sh[t - off] : 0;
        __syncthreads();
        sh[t] += u;
        __syncthreads();
    }
    if (t < nb) partl[t] = sh[t] - v;
    if (t == 1023) offs[N] = sh[1023];
}

__global__ void k_scan3(int* __restrict__ offs, const int* __restrict__ partl, int N) {
    int i = blockIdx.x * 256 + threadIdx.x;
    if (i < N) offs[i] += partl[blockIdx.x];
}

__global__ void k_fill_cur(const int* __restrict__ src, const int* __restrict__ dst,
                           const int* __restrict__ offs, int* __restrict__ cur,
                           int* __restrict__ col, int E) {
    int e = blockIdx.x * blockDim.x + threadIdx.x;
    if (e >= E) return;
    int d = dst[e];
    col[offs[d] + atomicAdd(&cur[d], 1)] = src[e];
}

__global__ void k_prescale(const float* __restrict__ x, const int* __restrict__ offs,
                           float4* __restrict__ xp4, int N) {
    int i = blockIdx.x * blockDim.x + threadIdx.x;
    if (i >= N) return;
    int d = offs[i+1] - offs[i];
    float di = rsqrtf((float)(d + 1));
    xp4[i] = make_float4(x[3*i] * di, x[3*i+1] * di, x[3*i+2] * di, di);
}

// ================= convs: G lanes/node, nontemporal float4 gathers ============

typedef float nat4 __attribute__((ext_vector_type(4)));

__device__ __forceinline__ float4 ldnt4(const float4* p) {
    nat4 v = __builtin_nontemporal_load((const nat4*)p);
    return make_float4(v.x, v.y, v.z, v.w);
}

__device__ __forceinline__ void gather_sum(const int* __restrict__ col,
                                           const float4* __restrict__ tab,
                                           int beg, int end, int g,
                                           float& s0, float& s1, float& s2) {
    int k = beg + g;
    for (; k + 3*G < end; k += 4*G) {
        int c0 = col[k], c1 = col[k+G], c2 = col[k+2*G], c3 = col[k+3*G];
        float4 v0 = ldnt4(&tab[c0]), v1 = ldnt4(&tab[c1]);
        float4 v2 = ldnt4(&tab[c2]), v3 = ldnt4(&tab[c3]);
        s0 += v0.x; s1 += v0.y; s2 += v0.z;
        s0 += v1.x; s1 += v1.y; s2 += v1.z;
        s0 += v2.x; s1 += v2.y; s2 += v2.z;
        s0 += v3.x; s1 += v3.y; s2 += v3.z;
    }
    for (; k < end; k += G) {
        float4 v = ldnt4(&tab[col[k]]);
        s0 += v.x; s1 += v.y; s2 += v.z;
    }
}

__global__ void k_conv1(const int* __restrict__ offs, const int* __restrict__ col,
                        const float4* __restrict__ xp4,
                        const float* __restrict__ W1, const float* __restrict__ b1,
                        const float* __restrict__ W2,
                        float4* __restrict__ h2p4, int N) {
    int tid = blockIdx.x * blockDim.x + threadIdx.x;
    int i = tid >> 3, g = tid & (G - 1);
    if (i >= N) return;
    float s0 = 0.f, s1 = 0.f, s2 = 0.f, di = 0.f;
    if (g == 0) {
        float4 self = xp4[i];          // self-loop term (already * di)
        s0 = self.x; s1 = self.y; s2 = self.z; di = self.w;
    }
    gather_sum(col, xp4, offs[i], offs[i+1], g, s0, s1, s2);
    #pragma unroll
    for (int off = G/2; off > 0; off >>= 1) {
        s0 += __shfl_down(s0, off, G);
        s1 += __shfl_down(s1, off, G);
        s2 += __shfl_down(s2, off, G);
    }
    if (g == 0) {
        float g0 = s0 * di, g1 = s1 * di, g2 = s2 * di;   // (Âx)[i]
        float o0 = 0.f, o1 = 0.f, o2 = 0.f;
        #pragma unroll
        for (int j = 0; j < 16; ++j) {
            float t = fmaxf(g0 * W1[j] + g1 * W1[16 + j] + g2 * W1[32 + j] + b1[j], 0.f);
            o0 += t * W2[3*j + 0];
            o1 += t * W2[3*j + 1];
            o2 += t * W2[3*j + 2];
        }
        h2p4[i] = make_float4(o0 * di, o1 * di, o2 * di, di);
    }
}

__global__ void k_conv2(const int* __restrict__ offs, const int* __restrict__ col,
                        const float4* __restrict__ h2p4,
                        const float* __restrict__ b2, const float* __restrict__ W3,
                        float* __restrict__ embed_out, float4* __restrict__ h3p4, int N) {
    int tid = blockIdx.x * blockDim.x + threadIdx.x;
    int i = tid >> 3, g = tid & (G - 1);
    if (i >= N) return;
    float s0 = 0.f, s1 = 0.f, s2 = 0.f, di = 0.f;
    if (g == 0) {
        float4 self = h2p4[i];
        s0 = self.x; s1 = self.y; s2 = self.z; di = self.w;
    }
    gather_sum(col, h2p4, offs[i], offs[i+1], g, s0, s1, s2);
    #pragma unroll
    for (int off = G/2; off > 0; off >>= 1) {
        s0 += __shfl_down(s0, off, G);
        s1 += __shfl_down(s1, off, G);
        s2 += __shfl_down(s2, off, G);
    }
    if (g == 0) {
        float t0 = s0 * di + b2[0];
        float t1 = s1 * di + b2[1];
        float t2 = s2 * di + b2[2];
        float inv = 1.0f / fmaxf(sqrtf(t0*t0 + t1*t1 + t2*t2), 1e-12f);
        float e0 = t0*inv, e1 = t1*inv, e2 = t2*inv;
        embed_out[3*i] = e0; embed_out[3*i+1] = e1; embed_out[3*i+2] = e2;
        h3p4[i] = make_float4((e0*W3[0] + e1*W3[3] + e2*W3[6]) * di,
                              (e0*W3[1] + e1*W3[4] + e2*W3[7]) * di,
                              (e0*W3[2] + e1*W3[5] + e2*W3[8]) * di, di);
    }
}

// conv3: deterministic pool reduction (per-wave LDS slots, no float atomics)
__global__ void k_conv3(const int* __restrict__ offs, const int* __restrict__ col,
                        const float4* __restrict__ h3p4,
                        const float* __restrict__ b3, const float* __restrict__ Wp,
                        const float* __restrict__ bp,
                        float* __restrict__ hout, float* __restrict__ pool, int N) {
    __shared__ float ws[4][3];  // 256 threads = 4 waves
    int tid = blockIdx.x * blockDim.x + threadIdx.x;
    int i = tid >> 3, g = tid & (G - 1);
    float p0 = 0.f, p1 = 0.f, p2 = 0.f;
    if (i < N) {
        float s0 = 0.f, s1 = 0.f, s2 = 0.f, di = 0.f;
        if (g == 0) {
            float4 self = h3p4[i];
            s0 = self.x; s1 = self.y; s2 = self.z; di = self.w;
        }
        gather_sum(col, h3p4, offs[i], offs[i+1], g, s0, s1, s2);
        #pragma unroll
        for (int off = G/2; off > 0; off >>= 1) {
            s0 += __shfl_down(s0, off, G);
            s1 += __shfl_down(s1, off, G);
            s2 += __shfl_down(s2, off, G);
        }
        if (g == 0) {
            float t0 = s0 * di + b3[0];
            float t1 = s1 * di + b3[1];
            float t2 = s2 * di + b3[2];
            p0 = t0*Wp[0] + t1*Wp[3] + t2*Wp[6] + bp[0];
            p1 = t0*Wp[1] + t1*Wp[4] + t2*Wp[7] + bp[1];
            p2 = t0*Wp[2] + t1*Wp[5] + t2*Wp[8] + bp[2];
            hout[3*i] = p0; hout[3*i+1] = p1; hout[3*i+2] = p2;
        }
    }
    #pragma unroll
    for (int off = 32; off > 0; off >>= 1) {
        p0 += __shfl_down(p0, off);
        p1 += __shfl_down(p1, off);
        p2 += __shfl_down(p2, off);
    }
    if ((threadIdx.x & 63) == 0) {
        int w = threadIdx.x >> 6;
        ws[w][0] = p0; ws[w][1] = p1; ws[w][2] = p2;
    }
    __syncthreads();
    if (threadIdx.x == 0) {
        pool[3*blockIdx.x]   = ws[0][0] + ws[1][0] + ws[2][0] + ws[3][0];
        pool[3*blockIdx.x+1] = ws[0][1] + ws[1][1] + ws[2][1] + ws[3][1];
        pool[3*blockIdx.x+2] = ws[0][2] + ws[1][2] + ws[2][2] + ws[3][2];
    }
}

// head: deterministic reduce of block partials, then logits + log_softmax
__global__ void k_head(const float* __restrict__ pool, int nb,
                       const float* __restrict__ Wl, const float* __restrict__ bl,
                       float* __restrict__ out, int N) {
    __shared__ float sh[12];  // 4 waves x 3
    int t = threadIdx.x;
    float p0 = 0.f, p1 = 0.f, p2 = 0.f;
    for (int k = t; k < nb; k += 256) {
        p0 += pool[3*k]; p1 += pool[3*k+1]; p2 += pool[3*k+2];
    }
    #pragma unroll
    for (int off = 32; off > 0; off >>= 1) {
        p0 += __shfl_down(p0, off);
        p1 += __shfl_down(p1, off);
        p2 += __shfl_down(p2, off);
    }
    if ((t & 63) == 0) {
        int w = t >> 6;
        sh[3*w] = p0; sh[3*w+1] = p1; sh[3*w+2] = p2;
    }
    __syncthreads();
    if (t == 0) {
        p0 = sh[0] + sh[3] + sh[6] + sh[9];
        p1 = sh[1] + sh[4] + sh[7] + sh[10];
        p2 = sh[2] + sh[5] + sh[8] + sh[11];
        p0 /= (float)N; p1 /= (float)N; p2 /= (float)N;
        float l[10];
        float m = -1e30f;
        #pragma unroll
        for (int j = 0; j < 10; ++j) {
            l[j] = p0 * Wl[j] + p1 * Wl[10 + j] + p2 * Wl[20 + j] + bl[j];
            m = fmaxf(m, l[j]);
        }
        float s = 0.f;
        #pragma unroll
        for (int j = 0; j < 10; ++j) s += expf(l[j] - m);
        float lse = logf(s) + m;
        #pragma unroll
        for (int j = 0; j < 10; ++j) out[j] = l[j] - lse;
    }
}

extern "C" void kernel_launch(void* const* d_in, const int* in_sizes, int n_in,
                              void* d_out, int out_size, void* d_ws, size_t ws_size,
                              hipStream_t stream) {
    const int N = N_NODES;
    const float* x  = (const float*)d_in[0];
    const int*   ei = (const int*)d_in[1];
    const int    E  = in_sizes[1] / 2;
    const int* src = ei;
    const int* dst = ei + E;
    const float* W1 = (const float*)d_in[2];
    const float* b1 = (const float*)d_in[3];
    const float* W2 = (const float*)d_in[4];
    const float* b2 = (const float*)d_in[5];
    const float* W3 = (const float*)d_in[6];
    const float* b3 = (const float*)d_in[7];
    const float* Wp = (const float*)d_in[8];
    const float* bp = (const float*)d_in[9];
    const float* Wl = (const float*)d_in[10];
    const float* bl = (const float*)d_in[11];

    float* out     = (float*)d_out;
    float* h_out   = out + 10;              // [N,3]
    float* emb_out = out + 10 + 3 * N;      // [N,3]

    const int B = 256;
    int gE = (E + B - 1) / B;
    int gN = (N + B - 1) / B;
    int gC = ((size_t)N * G + B - 1) / B;   // conv grid (3125 blocks)
    int PB = (N + 511) >> BSH;              // 196 buckets

    char* Wm = (char*)d_ws;
    size_t off = 0;
    auto alloc = [&](size_t elems) { void* p = Wm + off; off += elems * 4; return p; };

    // ---- bucket-path layout ----
    int*          col  = (int*)alloc((size_t)E);
    unsigned int* part = (unsigned int*)alloc((size_t)E);
    int*          hist = (int*)alloc((size_t)NB * NP);
    int*          base = (int*)alloc(NP + 1);
    int*          offs = (int*)alloc(N + 1);
    float4*       bufA = (float4*)alloc(4 * N);
    float4*       bufB = (float4*)alloc(4 * N);
    float*        pool = (float*)alloc(3 * (size_t)gC + 4);
    size_t need_bucket = off;

    int vec_ok = ((E & 3) == 0) &&
                 ((((uintptr_t)dst) & 15) == 0) &&
                 ((((uintptr_t)src) & 15) == 0);

    if (ws_size >= need_bucket) {
        k_hist<<<NB, TPP, 0, stream>>>(dst, E, vec_ok, hist);
        k_s1<<<1, NP, 0, stream>>>(hist, base, E);
        k_s2<<<NP, NB, 0, stream>>>(hist, base);
        k_part<<<NB, TPP, 0, stream>>>(src, dst, E, vec_ok, hist, part);
        k_csr<<<PB, 1024, 0, stream>>>(part, base, x, offs, bufA, col, N);
    } else {
        // ---- fallback layout ----
        off = 0;
        col  = (int*)alloc((size_t)E);
        int* deg = (int*)alloc(N);
        offs = (int*)alloc(N + 1);
        bufA = (float4*)alloc(4 * N);
        bufB = (float4*)alloc(4 * N);
        pool = (float*)alloc(3 * (size_t)gC + 4);
        int* partl = (int*)alloc(1024);
        int* cur = (int*)alloc(N);

        hipMemsetAsync(deg, 0, N * sizeof(int), stream);
        hipMemsetAsync(cur, 0, N * sizeof(int), stream);

        k_deg<<<gE, B, 0, stream>>>(dst, E, deg);
        k_scan1<<<gN, B, 0, stream>>>(deg, offs, partl, N);
        k_scan2<<<1, 1024, 0, stream>>>(partl, offs, gN, N);
        k_scan3<<<gN, B, 0, stream>>>(offs, partl, N);
        k_fill_cur<<<gE, B, 0, stream>>>(src, dst, offs, cur, col, E);
        k_prescale<<<gN, B, 0, stream>>>(x, offs, bufA, N);
    }

    // convs: G lanes/node, nontemporal float4 gathers, dinv carried in .w
    k_conv1<<<gC, B, 0, stream>>>(offs, col, bufA, W1, b1, W2, bufB, N);
    k_conv2<<<gC, B, 0, stream>>>(offs, col, bufB, b2, W3, emb_out, bufA, N);
    k_conv3<<<gC, B, 0, stream>>>(offs, col, bufA, b3, Wp, bp, h_out, pool, N);

    k_head<<<1, 256, 0, stream>>>(pool, gC, Wl, bl, out, N);
}

// Round 14
// 134.400 us; speedup vs baseline: 4.2692x; 1.4912x over previous
//
#include <hip/hip_runtime.h>
#include <math.h>
#include <stdint.h>

#define N_NODES 100000
#define NB 256          // partition blocks
#define NP 256          // buckets (dst >> 9), 512 nodes per bucket
#define BSH 9           // bucket shift
#define BMASK 511u      // node-in-bucket mask
#define G 8             // lanes per node in conv gathers

// ================= bucket-path CSR build (no global atomics) =================

__global__ void k_hist(const int* __restrict__ dst, int E,
                       int* __restrict__ hist) {
    __shared__ int bin[NP];
    if (threadIdx.x < NP) bin[threadIdx.x] = 0;
    __syncthreads();
    int ngroups = E >> 2;
    int gchunk = (ngroups + NB - 1) / NB;
    int gbeg = blockIdx.x * gchunk;
    int gend = gbeg + gchunk; if (gend > ngroups) gend = ngroups;
    const int4* d4 = (const int4*)dst;
    for (int g = gbeg + threadIdx.x; g < gend; g += 1024) {
        int4 d = d4[g];
        atomicAdd(&bin[d.x >> BSH], 1);
        atomicAdd(&bin[d.y >> BSH], 1);
        atomicAdd(&bin[d.z >> BSH], 1);
        atomicAdd(&bin[d.w >> BSH], 1);
    }
    if (blockIdx.x == 0) {
        for (int e = (ngroups << 2) + threadIdx.x; e < E; e += 1024)
            atomicAdd(&bin[dst[e] >> BSH], 1);
    }
    __syncthreads();
    if (threadIdx.x < NP)
        hist[blockIdx.x * NP + threadIdx.x] = bin[threadIdx.x];
}

__global__ void k_s1(const int* __restrict__ hist, int* __restrict__ base) {
    __shared__ int sh[NP];
    int b = threadIdx.x;
    int s = 0;
    #pragma unroll 8
    for (int k = 0; k < NB; ++k) s += hist[k * NP + b];
    sh[b] = s;
    __syncthreads();
    for (int off = 1; off < NP; off <<= 1) {
        int u = (b >= off) ? sh[b - off] : 0;
        __syncthreads();
        sh[b] += u;
        __syncthreads();
    }
    base[b] = sh[b] - s;
    if (b == NP - 1) base[NP] = sh[b];
}

__global__ void k_s2(int* __restrict__ hist, const int* __restrict__ base) {
    __shared__ int sh[NB];
    int b = blockIdx.x, t = threadIdx.x;
    int v = hist[t * NP + b];
    sh[t] = v;
    __syncthreads();
    for (int off = 1; off < NB; off <<= 1) {
        int u = (t >= off) ? sh[t - off] : 0;
        __syncthreads();
        sh[t] += u;
        __syncthreads();
    }
    hist[t * NP + b] = base[b] + sh[t] - v;
}

__global__ void k_part(const int* __restrict__ src, const int* __restrict__ dst,
                       int E, const int* __restrict__ hist,
                       unsigned int* __restrict__ part) {
    __shared__ int cur[NP];
    if (threadIdx.x < NP)
        cur[threadIdx.x] = hist[blockIdx.x * NP + threadIdx.x];
    __syncthreads();
    int ngroups = E >> 2;
    int gchunk = (ngroups + NB - 1) / NB;
    int gbeg = blockIdx.x * gchunk;
    int gend = gbeg + gchunk; if (gend > ngroups) gend = ngroups;
    const int4* d4 = (const int4*)dst;
    const int4* s4 = (const int4*)src;
    for (int g = gbeg + threadIdx.x; g < gend; g += 1024) {
        int4 d = d4[g];
        int4 s = s4[g];
        int p;
        p = atomicAdd(&cur[d.x >> BSH], 1);
        part[p] = ((unsigned)s.x << BSH) | ((unsigned)d.x & BMASK);
        p = atomicAdd(&cur[d.y >> BSH], 1);
        part[p] = ((unsigned)s.y << BSH) | ((unsigned)d.y & BMASK);
        p = atomicAdd(&cur[d.z >> BSH], 1);
        part[p] = ((unsigned)s.z << BSH) | ((unsigned)d.z & BMASK);
        p = atomicAdd(&cur[d.w >> BSH], 1);
        part[p] = ((unsigned)s.w << BSH) | ((unsigned)d.w & BMASK);
    }
    if (blockIdx.x == 0) {
        for (int e = (ngroups << 2) + threadIdx.x; e < E; e += 1024) {
            int d = dst[e];
            int p = atomicAdd(&cur[d >> BSH], 1);
            part[p] = ((unsigned)src[e] << BSH) | ((unsigned)d & BMASK);
        }
    }
}

__global__ void k_csr(const unsigned int* __restrict__ part, const int* __restrict__ base,
                      const float* __restrict__ x,
                      int* __restrict__ offs,
                      float4* __restrict__ xp4, int* __restrict__ col, int N) {
    __shared__ int cnt[512];
    __shared__ int scn[512];
    __shared__ int cur[512];
    int b = blockIdx.x, t = threadIdx.x;
    int lo = base[b], hi = base[b + 1];
    if (t < 512) cnt[t] = 0;
    __syncthreads();
    for (int e = lo + t; e < hi; e += 1024)
        atomicAdd(&cnt[part[e] & BMASK], 1);
    __syncthreads();
    int v = (t < 512) ? cnt[t] : 0;
    if (t < 512) scn[t] = v;
    __syncthreads();
    for (int off = 1; off < 512; off <<= 1) {
        int u = (t < 512 && t >= off) ? scn[t - off] : 0;
        __syncthreads();
        if (t < 512) scn[t] += u;
        __syncthreads();
    }
    if (t < 512) {
        int pos = lo + scn[t] - v;        // exclusive
        cur[t] = pos;
        int g = (b << BSH) + t;
        if (g < N) {
            offs[g] = pos;
            float di = rsqrtf((float)(v + 1));   // +1 self-loop
            xp4[g] = make_float4(x[3*g] * di, x[3*g+1] * di, x[3*g+2] * di, di);
        }
    }
    if (b == 0 && t == 0) offs[N] = base[(N_NODES + 511) >> BSH];
    __syncthreads();
    for (int e = lo + t; e < hi; e += 1024) {
        unsigned int w = part[e];
        int p = atomicAdd(&cur[w & BMASK], 1);
        col[p] = (int)(w >> BSH);
    }
}

// ================= fallback CSR build (global atomics) ==========

__global__ void k_deg(const int* __restrict__ dst, int E, int* __restrict__ deg) {
    int e = blockIdx.x * blockDim.x + threadIdx.x;
    if (e < E) atomicAdd(&deg[dst[e]], 1);
}

__global__ void k_scan1(const int* __restrict__ deg, int* __restrict__ offs,
                        int* __restrict__ partl, int N) {
    __shared__ int sh[256];
    int i = blockIdx.x * 256 + threadIdx.x;
    int t = threadIdx.x;
    int v = (i < N) ? deg[i] : 0;
    sh[t] = v;
    __syncthreads();
    #pragma unroll
    for (int off = 1; off < 256; off <<= 1) {
        int u = (t >= off) ? sh[t - off] : 0;
        __syncthreads();
        sh[t] += u;
        __syncthreads();
    }
    if (i < N) offs[i] = sh[t] - v;
    if (t == 255) partl[blockIdx.x] = sh[255];
}

__global__ void k_scan2(int* __restrict__ partl, int* __restrict__ offs, int nb, int N) {
    __shared__ int sh[1024];
    int t = threadIdx.x;
    int v = (t < nb) ? partl[t] : 0;
    sh[t] = v;
    __syncthreads();
    #pragma unroll
    for (int off = 1; off < 1024; off <<= 1) {
        int u = (t >= off) ? sh[t - off] : 0;
        __syncthreads();
        sh[t] += u;
        __syncthreads();
    }
    if (t < nb) partl[t] = sh[t] - v;
    if (t == 1023) offs[N] = sh[1023];
}

__global__ void k_scan3(int* __restrict__ offs, const int* __restrict__ partl, int N) {
    int i = blockIdx.x * 256 + threadIdx.x;
    if (i < N) offs[i] += partl[blockIdx.x];
}

__global__ void k_fill_cur(const int* __restrict__ src, const int* __restrict__ dst,
                           const int* __restrict__ offs, int* __restrict__ cur,
                           int* __restrict__ col, int E) {
    int e = blockIdx.x * blockDim.x + threadIdx.x;
    if (e >= E) return;
    int d = dst[e];
    col[offs[d] + atomicAdd(&cur[d], 1)] = src[e];
}

__global__ void k_prescale(const float* __restrict__ x, const int* __restrict__ offs,
                           float4* __restrict__ xp4, int N) {
    int i = blockIdx.x * blockDim.x + threadIdx.x;
    if (i >= N) return;
    int d = offs[i+1] - offs[i];
    float di = rsqrtf((float)(d + 1));
    xp4[i] = make_float4(x[3*i] * di, x[3*i+1] * di, x[3*i+2] * di, di);
}

// ================= convs: G lanes per node, float4 gathers, 4-deep unroll =====

__device__ __forceinline__ void gather_sum(const int* __restrict__ col,
                                           const float4* __restrict__ tab,
                                           int beg, int end, int g,
                                           float& s0, float& s1, float& s2) {
    int k = beg + g;
    for (; k + 3*G < end; k += 4*G) {
        int c0 = col[k], c1 = col[k+G], c2 = col[k+2*G], c3 = col[k+3*G];
        float4 v0 = tab[c0], v1 = tab[c1], v2 = tab[c2], v3 = tab[c3];
        s0 += v0.x; s1 += v0.y; s2 += v0.z;
        s0 += v1.x; s1 += v1.y; s2 += v1.z;
        s0 += v2.x; s1 += v2.y; s2 += v2.z;
        s0 += v3.x; s1 += v3.y; s2 += v3.z;
    }
    for (; k < end; k += G) {
        float4 v = tab[col[k]];
        s0 += v.x; s1 += v.y; s2 += v.z;
    }
}

__global__ void k_conv1(const int* __restrict__ offs, const int* __restrict__ col,
                        const float4* __restrict__ xp4,
                        const float* __restrict__ W1, const float* __restrict__ b1,
                        const float* __restrict__ W2,
                        float4* __restrict__ h2p4, int N) {
    int tid = blockIdx.x * blockDim.x + threadIdx.x;
    int i = tid >> 3, g = tid & (G - 1);
    if (i >= N) return;
    float s0 = 0.f, s1 = 0.f, s2 = 0.f, di = 0.f;
    if (g == 0) {
        float4 self = xp4[i];          // self-loop term (already * di)
        s0 = self.x; s1 = self.y; s2 = self.z; di = self.w;
    }
    gather_sum(col, xp4, offs[i], offs[i+1], g, s0, s1, s2);
    #pragma unroll
    for (int off = G/2; off > 0; off >>= 1) {
        s0 += __shfl_down(s0, off, G);
        s1 += __shfl_down(s1, off, G);
        s2 += __shfl_down(s2, off, G);
    }
    if (g == 0) {
        float g0 = s0 * di, g1 = s1 * di, g2 = s2 * di;   // (Âx)[i]
        float o0 = 0.f, o1 = 0.f, o2 = 0.f;
        #pragma unroll
        for (int j = 0; j < 16; ++j) {
            float t = fmaxf(g0 * W1[j] + g1 * W1[16 + j] + g2 * W1[32 + j] + b1[j], 0.f);
            o0 += t * W2[3*j + 0];
            o1 += t * W2[3*j + 1];
            o2 += t * W2[3*j + 2];
        }
        h2p4[i] = make_float4(o0 * di, o1 * di, o2 * di, di);
    }
}

__global__ void k_conv2(const int* __restrict__ offs, const int* __restrict__ col,
                        const float4* __restrict__ h2p4,
                        const float* __restrict__ b2, const float* __restrict__ W3,
                        float* __restrict__ embed_out, float4* __restrict__ h3p4, int N) {
    int tid = blockIdx.x * blockDim.x + threadIdx.x;
    int i = tid >> 3, g = tid & (G - 1);
    if (i >= N) return;
    float s0 = 0.f, s1 = 0.f, s2 = 0.f, di = 0.f;
    if (g == 0) {
        float4 self = h2p4[i];
        s0 = self.x; s1 = self.y; s2 = self.z; di = self.w;
    }
    gather_sum(col, h2p4, offs[i], offs[i+1], g, s0, s1, s2);
    #pragma unroll
    for (int off = G/2; off > 0; off >>= 1) {
        s0 += __shfl_down(s0, off, G);
        s1 += __shfl_down(s1, off, G);
        s2 += __shfl_down(s2, off, G);
    }
    if (g == 0) {
        float t0 = s0 * di + b2[0];
        float t1 = s1 * di + b2[1];
        float t2 = s2 * di + b2[2];
        float inv = 1.0f / fmaxf(sqrtf(t0*t0 + t1*t1 + t2*t2), 1e-12f);
        float e0 = t0*inv, e1 = t1*inv, e2 = t2*inv;
        embed_out[3*i] = e0; embed_out[3*i+1] = e1; embed_out[3*i+2] = e2;
        h3p4[i] = make_float4((e0*W3[0] + e1*W3[3] + e2*W3[6]) * di,
                              (e0*W3[1] + e1*W3[4] + e2*W3[7]) * di,
                              (e0*W3[2] + e1*W3[5] + e2*W3[8]) * di, di);
    }
}

// conv3: deterministic pool reduction (per-wave LDS slots, no float atomics)
__global__ void k_conv3(const int* __restrict__ offs, const int* __restrict__ col,
                        const float4* __restrict__ h3p4,
                        const float* __restrict__ b3, const float* __restrict__ Wp,
                        const float* __restrict__ bp,
                        float* __restrict__ hout, float* __restrict__ pool, int N) {
    __shared__ float ws[4][3];  // 256 threads = 4 waves
    int tid = blockIdx.x * blockDim.x + threadIdx.x;
    int i = tid >> 3, g = tid & (G - 1);
    float p0 = 0.f, p1 = 0.f, p2 = 0.f;
    if (i < N) {
        float s0 = 0.f, s1 = 0.f, s2 = 0.f, di = 0.f;
        if (g == 0) {
            float4 self = h3p4[i];
            s0 = self.x; s1 = self.y; s2 = self.z; di = self.w;
        }
        gather_sum(col, h3p4, offs[i], offs[i+1], g, s0, s1, s2);
        #pragma unroll
        for (int off = G/2; off > 0; off >>= 1) {
            s0 += __shfl_down(s0, off, G);
            s1 += __shfl_down(s1, off, G);
            s2 += __shfl_down(s2, off, G);
        }
        if (g == 0) {
            float t0 = s0 * di + b3[0];
            float t1 = s1 * di + b3[1];
            float t2 = s2 * di + b3[2];
            p0 = t0*Wp[0] + t1*Wp[3] + t2*Wp[6] + bp[0];
            p1 = t0*Wp[1] + t1*Wp[4] + t2*Wp[7] + bp[1];
            p2 = t0*Wp[2] + t1*Wp[5] + t2*Wp[8] + bp[2];
            hout[3*i] = p0; hout[3*i+1] = p1; hout[3*i+2] = p2;
        }
    }
    // wave reduce (only g==0 lanes nonzero), per-wave slot, serial block sum
    #pragma unroll
    for (int off = 32; off > 0; off >>= 1) {
        p0 += __shfl_down(p0, off);
        p1 += __shfl_down(p1, off);
        p2 += __shfl_down(p2, off);
    }
    if ((threadIdx.x & 63) == 0) {
        int w = threadIdx.x >> 6;
        ws[w][0] = p0; ws[w][1] = p1; ws[w][2] = p2;
    }
    __syncthreads();
    if (threadIdx.x == 0) {
        pool[3*blockIdx.x]   = ws[0][0] + ws[1][0] + ws[2][0] + ws[3][0];
        pool[3*blockIdx.x+1] = ws[0][1] + ws[1][1] + ws[2][1] + ws[3][1];
        pool[3*blockIdx.x+2] = ws[0][2] + ws[1][2] + ws[2][2] + ws[3][2];
    }
}

// head: deterministic reduce of block partials, then logits + log_softmax
__global__ void k_head(const float* __restrict__ pool, int nb,
                       const float* __restrict__ Wl, const float* __restrict__ bl,
                       float* __restrict__ out, int N) {
    __shared__ float sh[12];  // 4 waves x 3
    int t = threadIdx.x;
    float p0 = 0.f, p1 = 0.f, p2 = 0.f;
    for (int k = t; k < nb; k += 256) {
        p0 += pool[3*k]; p1 += pool[3*k+1]; p2 += pool[3*k+2];
    }
    #pragma unroll
    for (int off = 32; off > 0; off >>= 1) {
        p0 += __shfl_down(p0, off);
        p1 += __shfl_down(p1, off);
        p2 += __shfl_down(p2, off);
    }
    if ((t & 63) == 0) {
        int w = t >> 6;
        sh[3*w] = p0; sh[3*w+1] = p1; sh[3*w+2] = p2;
    }
    __syncthreads();
    if (t == 0) {
        p0 = sh[0] + sh[3] + sh[6] + sh[9];
        p1 = sh[1] + sh[4] + sh[7] + sh[10];
        p2 = sh[2] + sh[5] + sh[8] + sh[11];
        p0 /= (float)N; p1 /= (float)N; p2 /= (float)N;
        float l[10];
        float m = -1e30f;
        #pragma unroll
        for (int j = 0; j < 10; ++j) {
            l[j] = p0 * Wl[j] + p1 * Wl[10 + j] + p2 * Wl[20 + j] + bl[j];
            m = fmaxf(m, l[j]);
        }
        float s = 0.f;
        #pragma unroll
        for (int j = 0; j < 10; ++j) s += expf(l[j] - m);
        float lse = logf(s) + m;
        #pragma unroll
        for (int j = 0; j < 10; ++j) out[j] = l[j] - lse;
    }
}

extern "C" void kernel_launch(void* const* d_in, const int* in_sizes, int n_in,
                              void* d_out, int out_size, void* d_ws, size_t ws_size,
                              hipStream_t stream) {
    const int N = N_NODES;
    const float* x  = (const float*)d_in[0];
    const int*   ei = (const int*)d_in[1];
    const int    E  = in_sizes[1] / 2;
    const int* src = ei;
    const int* dst = ei + E;
    const float* W1 = (const float*)d_in[2];
    const float* b1 = (const float*)d_in[3];
    const float* W2 = (const float*)d_in[4];
    const float* b2 = (const float*)d_in[5];
    const float* W3 = (const float*)d_in[6];
    const float* b3 = (const float*)d_in[7];
    const float* Wp = (const float*)d_in[8];
    const float* bp = (const float*)d_in[9];
    const float* Wl = (const float*)d_in[10];
    const float* bl = (const float*)d_in[11];

    float* out     = (float*)d_out;
    float* h_out   = out + 10;              // [N,3]
    float* emb_out = out + 10 + 3 * N;      // [N,3]

    const int B = 256;
    int gE = (E + B - 1) / B;
    int gN = (N + B - 1) / B;
    int gC = ((size_t)N * G + B - 1) / B;   // conv grid (3125 blocks)
    int PB = (N + 511) >> BSH;              // 196 buckets

    char* Wm = (char*)d_ws;
    size_t off = 0;
    auto alloc = [&](size_t elems) { void* p = Wm + off; off += elems * 4; return p; };

    // ---- bucket-path layout ----
    int*          col  = (int*)alloc((size_t)E);
    unsigned int* part = (unsigned int*)alloc((size_t)E);
    int*          hist = (int*)alloc((size_t)NB * NP);
    int*          base = (int*)alloc(NP + 1);
    int*          offs = (int*)alloc(N + 1);
    float4*       bufA = (float4*)alloc(4 * N);
    float4*       bufB = (float4*)alloc(4 * N);
    float*        pool = (float*)alloc(3 * (size_t)gC + 4);
    size_t need_bucket = off;

    int vec_ok = ((E & 3) == 0) &&
                 ((((uintptr_t)dst) & 15) == 0) &&
                 ((((uintptr_t)src) & 15) == 0);

    if (ws_size >= need_bucket && vec_ok) {
        k_hist<<<NB, 1024, 0, stream>>>(dst, E, hist);
        k_s1<<<1, NP, 0, stream>>>(hist, base);
        k_s2<<<NP, NB, 0, stream>>>(hist, base);
        k_part<<<NB, 1024, 0, stream>>>(src, dst, E, hist, part);
        k_csr<<<PB, 1024, 0, stream>>>(part, base, x, offs, bufA, col, N);
    } else {
        // ---- fallback layout ----
        off = 0;
        col  = (int*)alloc((size_t)E);
        int* deg = (int*)alloc(N);
        offs = (int*)alloc(N + 1);
        bufA = (float4*)alloc(4 * N);
        bufB = (float4*)alloc(4 * N);
        pool = (float*)alloc(3 * (size_t)gC + 4);
        int* partl = (int*)alloc(1024);
        int* cur = (int*)alloc(N);

        hipMemsetAsync(deg, 0, N * sizeof(int), stream);
        hipMemsetAsync(cur, 0, N * sizeof(int), stream);

        k_deg<<<gE, B, 0, stream>>>(dst, E, deg);
        k_scan1<<<gN, B, 0, stream>>>(deg, offs, partl, N);
        k_scan2<<<1, 1024, 0, stream>>>(partl, offs, gN, N);
        k_scan3<<<gN, B, 0, stream>>>(offs, partl, N);
        k_fill_cur<<<gE, B, 0, stream>>>(src, dst, offs, cur, col, E);
        k_prescale<<<gN, B, 0, stream>>>(x, offs, bufA, N);
    }

    // convs: G lanes/node, float4 gathers, dinv carried in .w
    k_conv1<<<gC, B, 0, stream>>>(offs, col, bufA, W1, b1, W2, bufB, N);
    k_conv2<<<gC, B, 0, stream>>>(offs, col, bufB, b2, W3, emb_out, bufA, N);
    k_conv3<<<gC, B, 0, stream>>>(offs, col, bufA, b3, Wp, bp, h_out, pool, N);

    k_head<<<1, 256, 0, stream>>>(pool, gC, Wl, bl, out, N);
}